// Round 16
// baseline (393.041 us; speedup 1.0000x reference)
//
#include <hip/hip_runtime.h>
#include <hip/hip_bf16.h>

typedef __bf16 bf16x8 __attribute__((ext_vector_type(8)));
typedef float f32x4 __attribute__((ext_vector_type(4)));
typedef float f32x2 __attribute__((ext_vector_type(2)));

__device__ __forceinline__ float bf2f(unsigned short b) {
  unsigned int u = ((unsigned int)b) << 16;
  return __builtin_bit_cast(float, u);
}
__device__ __forceinline__ unsigned short f2bf(float f) {
  unsigned int u = __builtin_bit_cast(unsigned int, f);
  unsigned int r = u + 0x7fffu + ((u >> 16) & 1u);
  return (unsigned short)(r >> 16);
}
__device__ __forceinline__ f32x2 unpack2(unsigned int u) {
  f32x2 r;
  r.x = __builtin_bit_cast(float, u << 16);
  r.y = __builtin_bit_cast(float, u & 0xffff0000u);
  return r;
}

__device__ __forceinline__ void gload16(const void* g, void* l) {
  typedef __attribute__((address_space(1))) const void* gp_t;
  typedef __attribute__((address_space(3))) void* lp_t;
  __builtin_amdgcn_global_load_lds((gp_t)g, (lp_t)l, 16, 0, 0);
}

// fast GELU: x * sigmoid(1.5958(x + 0.044715 x^3)), |err vs exact erf| <= ~5e-4.
__device__ __forceinline__ f32x2 gelu2(f32x2 x) {
  f32x2 m = x * x;
  f32x2 t = m * (-0.10295273f) + (-2.3021967f);
  f32x2 u = x * t;
  f32x2 e;
  e.x = __builtin_amdgcn_exp2f(u.x);
  e.y = __builtin_amdgcn_exp2f(u.y);
  f32x2 d = e + 1.0f;
  f32x2 r;
  r.x = __builtin_amdgcn_rcpf(d.x);
  r.y = __builtin_amdgcn_rcpf(d.y);
  return x * r;
}
__device__ __forceinline__ unsigned int cvt_pk_bf16(float lo, float hi) {
  unsigned int r;
  asm("v_cvt_pk_bf16_f32 %0, %1, %2" : "=v"(r) : "v"(lo), "v"(hi));
  return r;
}

// ---------------- fused weight prep (one dispatch) ----------------
__global__ __launch_bounds__(256) void prep_all(
    const float* __restrict__ c1w, const float* __restrict__ r1w,
    const float* __restrict__ c2w, const float* __restrict__ r2w,
    const float* __restrict__ c3w, const float* __restrict__ r3w, const float* __restrict__ r3b,
    const float* __restrict__ c1b, const float* __restrict__ r1b,
    const float* __restrict__ c2b, const float* __restrict__ r2b,
    const float* __restrict__ d1wc, const float* __restrict__ d1bc,
    const float* __restrict__ d1wr, const float* __restrict__ d1br,
    const float* __restrict__ d2wc, const float* __restrict__ d2bc,
    const float* __restrict__ d2wr, const float* __restrict__ d2br,
    unsigned short* __restrict__ w1cat, unsigned short* __restrict__ w2cat,
    unsigned short* __restrict__ c3wb, unsigned short* __restrict__ wr3pad,
    float* __restrict__ br3pad, float* __restrict__ b1cat, float* __restrict__ b2cat,
    float* __restrict__ wd1, float* __restrict__ bd1,
    float* __restrict__ wd2, float* __restrict__ bd2) {
  int i = blockIdx.x * 256 + threadIdx.x;  // 262144
  {
    int which = i >> 16, j = i & 65535;
    float v = (which == 0) ? c1w[j] : (which == 1) ? r1w[j] : (which == 2) ? c2w[j] : r2w[j];
    unsigned short* dst = (which < 2) ? (w1cat + which * 65536) : (w2cat + (which - 2) * 65536);
    dst[j] = f2bf(v);
  }
  if (i < 32768) {
    int r = i >> 8, c = i & 255;
    wr3pad[i] = (r < 68) ? f2bf(r3w[r * 256 + c]) : (unsigned short)0;
    if (i < 128) br3pad[i] = (i < 68) ? r3b[i] : 0.f;
  }
  if (i < 256) c3wb[i] = f2bf(c3w[i]);
  if (i < 4608) {
    int tap = i >> 9, ch = i & 511, cc = ch & 255;
    wd1[i] = (ch < 256) ? d1wc[cc * 9 + tap] : d1wr[cc * 9 + tap];
    wd2[i] = (ch < 256) ? d2wc[cc * 9 + tap] : d2wr[cc * 9 + tap];
  }
  if (i < 512) {
    bd1[i] = (i < 256) ? d1bc[i] : d1br[i & 255];
    bd2[i] = (i < 256) ? d2bc[i] : d2br[i & 255];
    b1cat[i] = (i < 256) ? c1b[i] : r1b[i & 255];
    b2cat[i] = (i < 256) ? c2b[i] : r2b[i & 255];
  }
}

// ---------------- fc1 GEMM: fp32 A loaded ONCE to LDS (prologue), B dbuf --------
// Out[m,n] = bf16(X[m,:256]) . W[n,:256] + bias[n].  X fp32.
// LDS: A 64KB (all K, swizzled), B 2x8KB double-buffer.  grid = 1024*4.
__global__ __launch_bounds__(256, 2) void gemm_f32a(
    const float* __restrict__ X,
    const unsigned short* __restrict__ W,
    const float* __restrict__ bias,
    unsigned short* __restrict__ Out, int ldo, int lnN) {
  __shared__ unsigned short ldsA[32768];     // 128 rows x 32 granules x 8 shorts
  __shared__ unsigned short ldsB[2][4096];   // 2 x (128 rows x 4 granules x 8)
  const int nwg = gridDim.x;
  const int bid = blockIdx.x;
  const int wg = (bid & 7) * (nwg >> 3) + (bid >> 3);
  const int mtile = wg >> lnN;
  const int ntile = wg & ((1 << lnN) - 1);
  const long row0 = (long)mtile * 128;
  const int col0 = ntile * 128;

  const int tid = threadIdx.x;
  const int lane = tid & 63;
  const int wid = tid >> 6;
  const int wr = (wid >> 1) * 64;
  const int wc = (wid & 1) * 64;
  const int rr = lane & 15;
  const int gk = lane >> 4;
  const int swz = (rr >> 1) & 3;

  const int srow_l = (wid << 4) + (lane >> 2);
  const int sgl = lane & 3;

  // ---- prologue: load A fp32 -> bf16 -> swizzled LDS (once) ----
  {
    const int arow = tid >> 1;
    const int cpart = tid & 1;
    const float* src = X + (row0 + arow) * 256L + cpart * 128;
    const int rswz = (arow >> 1) & 3;
    #pragma unroll 4
    for (int j = 0; j < 16; j++) {
      const int glog = cpart * 16 + j;
      const float4 v0 = *(const float4*)(src + j * 8);
      const float4 v1 = *(const float4*)(src + j * 8 + 4);
      uint4 pk;
      pk.x = cvt_pk_bf16(v0.x, v0.y);
      pk.y = cvt_pk_bf16(v0.z, v0.w);
      pk.z = cvt_pk_bf16(v1.x, v1.y);
      pk.w = cvt_pk_bf16(v1.z, v1.w);
      const int phys = (glog & ~3) | ((glog & 3) ^ rswz);
      *(uint4*)&ldsA[(arow * 32 + phys) * 8] = pk;
    }
  }

  auto stageB = [&](int buf, int k0) {
    #pragma unroll
    for (int j = 0; j < 2; j++) {
      const int slotbase = j * 256 + (wid << 6);
      const int row = j * 64 + srow_l;
      const int g = sgl ^ ((row >> 1) & 3);
      gload16(W + (long)(col0 + row) * 256 + k0 + g * 8,
              &ldsB[buf][slotbase * 8]);
    }
  };

  f32x4 acc[4][4] = {};
  stageB(0, 0);
  asm volatile("s_waitcnt vmcnt(0) lgkmcnt(0)" ::: "memory");
  __builtin_amdgcn_s_barrier();

  #pragma unroll
  for (int ks = 0; ks < 8; ks++) {
    if (ks < 7) {
      stageB((ks + 1) & 1, (ks + 1) * 32);
      asm volatile("s_waitcnt vmcnt(2)" ::: "memory");
    } else {
      asm volatile("s_waitcnt vmcnt(0)" ::: "memory");
    }
    __builtin_amdgcn_s_barrier();
    asm volatile("" ::: "memory");
    const unsigned short* bufB = ldsB[ks & 1];
    bf16x8 af[4], bf[4];
    #pragma unroll
    for (int mi = 0; mi < 4; mi++)
      af[mi] = __builtin_bit_cast(bf16x8,
          *(const uint4*)&ldsA[((wr + mi * 16 + rr) * 32 + ks * 4 + (gk ^ swz)) * 8]);
    #pragma unroll
    for (int ni = 0; ni < 4; ni++)
      bf[ni] = __builtin_bit_cast(bf16x8,
          *(const uint4*)&bufB[((wc + ni * 16 + rr) * 4 + (gk ^ swz)) * 8]);
    #pragma unroll
    for (int mi = 0; mi < 4; mi++)
      #pragma unroll
      for (int ni = 0; ni < 4; ni++)
        acc[mi][ni] = __builtin_amdgcn_mfma_f32_16x16x32_bf16(af[mi], bf[ni], acc[mi][ni], 0, 0, 0);
    asm volatile("" ::: "memory");
    __builtin_amdgcn_s_barrier();
  }

  #pragma unroll
  for (int mi = 0; mi < 4; mi++) {
    const int rbase = wr + mi * 16 + (lane >> 4) * 4;
    #pragma unroll
    for (int ni = 0; ni < 4; ni++) {
      const int c_ = wc + ni * 16 + (lane & 15);
      const float bv = bias[col0 + c_];
      #pragma unroll
      for (int r = 0; r < 4; r++) {
        Out[(row0 + rbase + r) * (long)ldo + col0 + c_] = f2bf(acc[mi][ni][r] + bv);
      }
    }
  }
}

// ---------------- GEMM: 128x128, 2-buffer, counted vmcnt(4), bounds(256,3) -------
// Out[m,n] = A[m,:256] . W[n,:256] + bias[n].
// OutF (optional): fp32 secondary output, N-cols < 68 only (fc3 reg_pred path).
__global__ __launch_bounds__(256, 3) void gemm_glds(
    const unsigned short* __restrict__ A, int lda, int zAoff,
    const unsigned short* __restrict__ W, int zWoff,
    const float* __restrict__ bias, int zBoff,
    unsigned short* __restrict__ Out, int ldo, int zOoff, int lnN,
    float* __restrict__ OutF) {
  __shared__ unsigned short lds[2][8192];   // 32 KiB: 2 bufs x (A 8KB | B 8KB)
  const int z = blockIdx.z;
  const unsigned short* Az = A + (long)z * zAoff;
  const unsigned short* Wz = W + (long)z * zWoff;
  const float* biasz = bias + z * zBoff;
  unsigned short* Outz = Out + (long)z * zOoff;

  const int nwg = gridDim.x;
  const int bid = blockIdx.x;
  const int wg = (bid & 7) * (nwg >> 3) + (bid >> 3);
  const int mtile = wg >> lnN;
  const int ntile = wg & ((1 << lnN) - 1);
  const long row0 = (long)mtile * 128;
  const int col0 = ntile * 128;

  const int tid = threadIdx.x;
  const int lane = tid & 63;
  const int wid = tid >> 6;
  const int wr = (wid >> 1) * 64;
  const int wc = (wid & 1) * 64;
  const int rr = lane & 15;
  const int gk = lane >> 4;
  const int swz = (rr >> 1) & 3;

  const int srow_l = (wid << 4) + (lane >> 2);
  const int sgl = lane & 3;

  f32x4 acc[4][4] = {};

  auto stage = [&](int buf, int k0) {
    #pragma unroll
    for (int j = 0; j < 4; j++) {
      const int slotbase = j * 256 + (wid << 6);
      unsigned short* ldst = &lds[buf][slotbase * 8];
      const int row = (j & 1) * 64 + srow_l;
      const int g = sgl ^ ((row >> 1) & 3);
      const unsigned short* src;
      if (j < 2) src = Az + (row0 + row) * (long)lda + k0 + g * 8;
      else       src = Wz + (long)(col0 + row) * 256 + k0 + g * 8;
      gload16(src, ldst);
    }
  };

  stage(0, 0);
  #pragma unroll
  for (int ks = 0; ks < 8; ks++) {
    if (ks < 7) {
      stage((ks + 1) & 1, (ks + 1) * 32);
      asm volatile("s_waitcnt vmcnt(4)" ::: "memory");
    } else {
      asm volatile("s_waitcnt vmcnt(0)" ::: "memory");
    }
    __builtin_amdgcn_s_barrier();
    asm volatile("" ::: "memory");
    const unsigned short* buf = lds[ks & 1];
    bf16x8 af[4], bf[4];
    #pragma unroll
    for (int mi = 0; mi < 4; mi++)
      af[mi] = __builtin_bit_cast(bf16x8,
          *(const uint4*)&buf[(wr + mi * 16 + rr) * 32 + ((gk ^ swz) * 8)]);
    #pragma unroll
    for (int ni = 0; ni < 4; ni++)
      bf[ni] = __builtin_bit_cast(bf16x8,
          *(const uint4*)&buf[4096 + (wc + ni * 16 + rr) * 32 + ((gk ^ swz) * 8)]);
    #pragma unroll
    for (int mi = 0; mi < 4; mi++)
      #pragma unroll
      for (int ni = 0; ni < 4; ni++)
        acc[mi][ni] = __builtin_amdgcn_mfma_f32_16x16x32_bf16(af[mi], bf[ni], acc[mi][ni], 0, 0, 0);
    asm volatile("" ::: "memory");
    __builtin_amdgcn_s_barrier();
  }

  #pragma unroll
  for (int mi = 0; mi < 4; mi++) {
    const int rbase = wr + mi * 16 + (lane >> 4) * 4;
    #pragma unroll
    for (int ni = 0; ni < 4; ni++) {
      const int c_ = wc + ni * 16 + (lane & 15);
      const float bv = biasz[col0 + c_];
      #pragma unroll
      for (int r = 0; r < 4; r++) {
        const float val = acc[mi][ni][r] + bv;
        Outz[(row0 + rbase + r) * (long)ldo + col0 + c_] = f2bf(val);
        if (OutF != nullptr && c_ < 68)
          OutF[(row0 + rbase + r) * 68L + c_] = val;
      }
    }
  }
}

// ---------------- depthwise 3x3 + bias + fast GELU, 4 pixels/thread ----------------
// CLS: lanes 0-31 (c-branch) don't store; instead compute fc3_c dot (256ch) -> cls_logit.
template <bool CLS>
__global__ __launch_bounds__(256) void dwconv_gelu4(
    const unsigned short* __restrict__ In,
    const float* __restrict__ Wt, const float* __restrict__ Bt,
    unsigned short* __restrict__ Out,
    const unsigned short* __restrict__ Wc3, const float* __restrict__ bc3,
    float* __restrict__ cls_logit) {
  const int t = blockIdx.x * 256 + threadIdx.x;  // 32768 quads * 64 groups
  const int g = t & 63;
  const int p = t >> 6;
  const int n = p >> 10;
  const int h = (p >> 4) & 63;
  const int w0 = (p & 15) << 2;
  const int cbase = g << 3;
  f32x2 acc[4][4];
  {
    float4 b0 = *(const float4*)(Bt + cbase);
    float4 b1 = *(const float4*)(Bt + cbase + 4);
    f32x2 bb[4];
    bb[0].x = b0.x; bb[0].y = b0.y; bb[1].x = b0.z; bb[1].y = b0.w;
    bb[2].x = b1.x; bb[2].y = b1.y; bb[3].x = b1.z; bb[3].y = b1.w;
    #pragma unroll
    for (int k = 0; k < 4; k++)
      #pragma unroll
      for (int i = 0; i < 4; i++) acc[k][i] = bb[i];
  }
  #pragma unroll
  for (int dy = -1; dy <= 1; dy++) {
    const int hh = h + dy;
    if (hh < 0 || hh > 63) continue;           // wave-uniform
    const float* wbase = Wt + ((dy + 1) * 3) * 512 + cbase;
    f32x2 wt[3][4];
    #pragma unroll
    for (int j = 0; j < 3; j++) {
      float4 a0 = *(const float4*)(wbase + j * 512);
      float4 a1 = *(const float4*)(wbase + j * 512 + 4);
      wt[j][0].x = a0.x; wt[j][0].y = a0.y; wt[j][1].x = a0.z; wt[j][1].y = a0.w;
      wt[j][2].x = a1.x; wt[j][2].y = a1.y; wt[j][3].x = a1.z; wt[j][3].y = a1.w;
    }
    const long rowtok = (long)(((n << 6) + hh) << 6);
    f32x2 f[6][4];
    #pragma unroll
    for (int d = 0; d < 6; d++) {
      const int col = w0 - 1 + d;
      uint4 v = {0u, 0u, 0u, 0u};
      if (col >= 0 && col < 64)                // only d=0/d=5 can fail; wave-uniform
        v = *(const uint4*)(In + (rowtok + col) * 512 + cbase);
      f[d][0] = unpack2(v.x); f[d][1] = unpack2(v.y);
      f[d][2] = unpack2(v.z); f[d][3] = unpack2(v.w);
    }
    #pragma unroll
    for (int k = 0; k < 4; k++)
      #pragma unroll
      for (int j = 0; j < 3; j++)
        #pragma unroll
        for (int i = 0; i < 4; i++)
          acc[k][i] += f[k + j][i] * wt[j][i];
  }
  f32x2 w3[4];
  if (CLS) {
    const int cc = cbase & 255;
    uint4 wv = *(const uint4*)(Wc3 + cc);
    w3[0] = unpack2(wv.x); w3[1] = unpack2(wv.y);
    w3[2] = unpack2(wv.z); w3[3] = unpack2(wv.w);
  }
  const long mbase = ((long)((n << 6) + h) << 6) + w0;
  float s[4];
  #pragma unroll
  for (int k = 0; k < 4; k++) {
    __align__(16) unsigned int ov[4];
    f32x2 ge[4];
    #pragma unroll
    for (int i = 0; i < 4; i++) {
      ge[i] = gelu2(acc[k][i]);
      ov[i] = cvt_pk_bf16(ge[i].x, ge[i].y);
    }
    if (!CLS || cbase >= 256)
      *(uint4*)(Out + (mbase + k) * 512 + cbase) = *(uint4*)ov;
    if (CLS) {
      f32x2 sp = ge[0] * w3[0] + ge[1] * w3[1] + ge[2] * w3[2] + ge[3] * w3[3];
      s[k] = sp.x + sp.y;
    }
  }
  if (CLS) {
    #pragma unroll
    for (int k = 0; k < 4; k++) {
      #pragma unroll
      for (int m = 16; m >= 1; m >>= 1) s[k] += __shfl_xor(s[k], m);
    }
    if (g == 0) {
      float b = bc3[0];
      float4 o;
      o.x = s[0] + b; o.y = s[1] + b; o.z = s[2] + b; o.w = s[3] + b;
      *(float4*)(cls_logit + mbase) = o;
    }
  }
}

// ---------------- post: softmax-17, boxes, top4, q-net, cls fuse ----------------
// out_reg is written by the fc3 GEMM; here only cls + boxes.
__global__ __launch_bounds__(256) void post_kernel(
    const unsigned short* __restrict__ RP,
    const float* __restrict__ cls_logit,
    const float* __restrict__ rc1_w, const float* __restrict__ rc1_b,
    const float* __restrict__ rc2_w, const float* __restrict__ rc2_b,
    float* __restrict__ out_cls, float* __restrict__ out_boxes) {
  int m = blockIdx.x * 256 + threadIdx.x;
  const unsigned short* rp = RP + (long)m * 128;
  __align__(16) unsigned short raw[72];
  #pragma unroll
  for (int q = 0; q < 9; q++)
    *(uint4*)(raw + q * 8) = *(const uint4*)(rp + q * 8);
  float stat[20];
  float4 boxes;
  #pragma unroll
  for (int s = 0; s < 4; s++) {
    float v[17];
    float mx = -1e30f;
    #pragma unroll
    for (int i = 0; i < 17; i++) {
      v[i] = bf2f(raw[s * 17 + i]);
      mx = fmaxf(mx, v[i]);
    }
    float sum = 0.f;
    #pragma unroll
    for (int i = 0; i < 17; i++) { v[i] = __expf(v[i] - mx); sum += v[i]; }
    float inv = 1.f / sum;
    float dist = 0.f;
    #pragma unroll
    for (int i = 0; i < 17; i++) { v[i] *= inv; dist += v[i] * (float)i; }
    ((float*)&boxes)[s] = dist * 0.0625f;
    float tk[4];
    #pragma unroll
    for (int t = 0; t < 4; t++) {
      float bm = v[0]; int bi = 0;
      #pragma unroll
      for (int i = 1; i < 17; i++) {
        if (v[i] > bm) { bm = v[i]; bi = i; }
      }
      tk[t] = bm;
      #pragma unroll
      for (int i = 0; i < 17; i++)
        if (i == bi) v[i] = -1.f;
    }
    stat[s * 5 + 0] = tk[0]; stat[s * 5 + 1] = tk[1];
    stat[s * 5 + 2] = tk[2]; stat[s * 5 + 3] = tk[3];
    stat[s * 5 + 4] = 0.25f * (tk[0] + tk[1] + tk[2] + tk[3]);
  }
  *(float4*)(out_boxes + (long)m * 4) = boxes;
  float z = 0.f;
  #pragma unroll
  for (int o = 0; o < 64; o++) {
    float q = rc1_b[o];
    #pragma unroll
    for (int c = 0; c < 20; c++) q += rc1_w[o * 20 + c] * stat[c];
    q = fmaxf(q, 0.f);
    z += q * rc2_w[o];
  }
  z += rc2_b[0];
  float q2 = 1.f / (1.f + __expf(-z));
  float cl = 1.f / (1.f + __expf(-cls_logit[m]));
  out_cls[m] = cl * q2;
}

extern "C" void kernel_launch(void* const* d_in, const int* in_sizes, int n_in,
                              void* d_out, int out_size, void* d_ws, size_t ws_size,
                              hipStream_t stream) {
  const float* x       = (const float*)d_in[0];
  const float* c_fc1_w = (const float*)d_in[1];
  const float* c_fc1_b = (const float*)d_in[2];
  const float* c_dw1_w = (const float*)d_in[3];
  const float* c_dw1_b = (const float*)d_in[4];
  const float* c_fc2_w = (const float*)d_in[5];
  const float* c_fc2_b = (const float*)d_in[6];
  const float* c_dw2_w = (const float*)d_in[7];
  const float* c_dw2_b = (const float*)d_in[8];
  const float* c_fc3_w = (const float*)d_in[9];
  const float* c_fc3_b = (const float*)d_in[10];
  const float* r_fc1_w = (const float*)d_in[11];
  const float* r_fc1_b = (const float*)d_in[12];
  const float* r_dw1_w = (const float*)d_in[13];
  const float* r_dw1_b = (const float*)d_in[14];
  const float* r_fc2_w = (const float*)d_in[15];
  const float* r_fc2_b = (const float*)d_in[16];
  const float* r_dw2_w = (const float*)d_in[17];
  const float* r_dw2_b = (const float*)d_in[18];
  const float* r_fc3_w = (const float*)d_in[19];
  const float* r_fc3_b = (const float*)d_in[20];
  const float* rc1_w   = (const float*)d_in[21];
  const float* rc1_b   = (const float*)d_in[22];
  const float* rc2_w   = (const float*)d_in[23];
  const float* rc2_b   = (const float*)d_in[24];

  char* ws = (char*)d_ws;
  unsigned short* Hbuf = (unsigned short*)ws;                       // 128 MiB
  unsigned short* Gbuf = (unsigned short*)(ws + 134217728L);        // 128 MiB
  unsigned short* RP   = (unsigned short*)(ws + 268435456L);        // 32 MiB
  float* cls_logit     = (float*)(ws + 301989888L);                 // 512 KiB
  char* wb             = ws + 302514176L;
  unsigned short* w1cat  = (unsigned short*)wb;          // 131072 bf16 (c_fc1|r_fc1)
  unsigned short* w2cat  = w1cat + 131072;               // 131072 bf16 (c_fc2|r_fc2)
  unsigned short* c3wb   = w2cat + 131072;               // 256
  unsigned short* wr3pad = c3wb + 256;                   // 32768
  float* br3pad = (float*)(wr3pad + 32768);              // 128
  float* b1cat  = br3pad + 128;                          // 512
  float* b2cat  = b1cat + 512;                           // 512
  float* wd1    = b2cat + 512;                           // 4608
  float* bd1    = wd1 + 4608;                            // 512
  float* wd2    = bd1 + 512;                             // 4608
  float* bd2    = wd2 + 4608;                            // 512

  float* out_cls   = (float*)d_out;
  float* out_boxes = out_cls + 131072;
  float* out_reg   = out_boxes + 524288;

  prep_all<<<1024, 256, 0, stream>>>(
      c_fc1_w, r_fc1_w, c_fc2_w, r_fc2_w, c_fc3_w, r_fc3_w, r_fc3_b,
      c_fc1_b, r_fc1_b, c_fc2_b, r_fc2_b,
      c_dw1_w, c_dw1_b, r_dw1_w, r_dw1_b,
      c_dw2_w, c_dw2_b, r_dw2_w, r_dw2_b,
      w1cat, w2cat, c3wb, wr3pad, br3pad, b1cat, b2cat,
      wd1, bd1, wd2, bd2);

  // fc1: A = x fp32 (prologue-staged once per block), N=512 (nN=4)
  gemm_f32a<<<dim3(4096, 1, 1), 256, 0, stream>>>(
      x, w1cat, b1cat, Hbuf, 512, 2);
  // dwconv1 + gelu (stores both halves)
  dwconv_gelu4<false><<<8192, 256, 0, stream>>>(Hbuf, wd1, bd1, Gbuf,
                                                nullptr, nullptr, nullptr);
  // fc2: branches via z (nN=2 per branch)
  gemm_glds<<<dim3(2048, 1, 2), 256, 0, stream>>>(
      Gbuf, 512, 256, w2cat, 65536, b2cat, 256, Hbuf, 512, 256, 1, nullptr);
  // dwconv2 + gelu + fused cls dot (stores only r-half)
  dwconv_gelu4<true><<<8192, 256, 0, stream>>>(Hbuf, wd2, bd2, Gbuf,
                                               c3wb, c_fc3_b, cls_logit);
  // fc3 (r-half): bf16 RP for post + fp32 out_reg directly
  gemm_glds<<<dim3(1024, 1, 1), 256, 0, stream>>>(
      Gbuf + 256, 512, 0, wr3pad, 0, br3pad, 0, RP, 128, 0, 0, out_reg);
  // post (cls + boxes only)
  post_kernel<<<512, 256, 0, stream>>>(RP, cls_logit, rc1_w, rc1_b, rc2_w, rc2_b,
                                       out_cls, out_boxes);
}

// Round 17
// 366.655 us; speedup vs baseline: 1.0720x; 1.0720x over previous
//
#include <hip/hip_runtime.h>
#include <hip/hip_bf16.h>

typedef __bf16 bf16x8 __attribute__((ext_vector_type(8)));
typedef float f32x4 __attribute__((ext_vector_type(4)));
typedef float f32x2 __attribute__((ext_vector_type(2)));

__device__ __forceinline__ float bf2f(unsigned short b) {
  unsigned int u = ((unsigned int)b) << 16;
  return __builtin_bit_cast(float, u);
}
__device__ __forceinline__ unsigned short f2bf(float f) {
  unsigned int u = __builtin_bit_cast(unsigned int, f);
  unsigned int r = u + 0x7fffu + ((u >> 16) & 1u);
  return (unsigned short)(r >> 16);
}
__device__ __forceinline__ f32x2 unpack2(unsigned int u) {
  f32x2 r;
  r.x = __builtin_bit_cast(float, u << 16);
  r.y = __builtin_bit_cast(float, u & 0xffff0000u);
  return r;
}

__device__ __forceinline__ void gload16(const void* g, void* l) {
  typedef __attribute__((address_space(1))) const void* gp_t;
  typedef __attribute__((address_space(3))) void* lp_t;
  __builtin_amdgcn_global_load_lds((gp_t)g, (lp_t)l, 16, 0, 0);
}

// fast GELU: x * sigmoid(1.5958(x + 0.044715 x^3)), |err vs exact erf| <= ~5e-4.
__device__ __forceinline__ f32x2 gelu2(f32x2 x) {
  f32x2 m = x * x;
  f32x2 t = m * (-0.10295273f) + (-2.3021967f);
  f32x2 u = x * t;
  f32x2 e;
  e.x = __builtin_amdgcn_exp2f(u.x);
  e.y = __builtin_amdgcn_exp2f(u.y);
  f32x2 d = e + 1.0f;
  f32x2 r;
  r.x = __builtin_amdgcn_rcpf(d.x);
  r.y = __builtin_amdgcn_rcpf(d.y);
  return x * r;
}
__device__ __forceinline__ unsigned int cvt_pk_bf16(float lo, float hi) {
  unsigned int r;
  asm("v_cvt_pk_bf16_f32 %0, %1, %2" : "=v"(r) : "v"(lo), "v"(hi));
  return r;
}

// ---------------- fused weight prep (one dispatch) ----------------
__global__ __launch_bounds__(256) void prep_all(
    const float* __restrict__ c1w, const float* __restrict__ r1w,
    const float* __restrict__ c2w, const float* __restrict__ r2w,
    const float* __restrict__ c3w, const float* __restrict__ r3w, const float* __restrict__ r3b,
    const float* __restrict__ c1b, const float* __restrict__ r1b,
    const float* __restrict__ c2b, const float* __restrict__ r2b,
    const float* __restrict__ d1wc, const float* __restrict__ d1bc,
    const float* __restrict__ d1wr, const float* __restrict__ d1br,
    const float* __restrict__ d2wc, const float* __restrict__ d2bc,
    const float* __restrict__ d2wr, const float* __restrict__ d2br,
    unsigned short* __restrict__ w1cat, unsigned short* __restrict__ w2cat,
    unsigned short* __restrict__ c3wb, unsigned short* __restrict__ wr3pad,
    float* __restrict__ br3pad, float* __restrict__ b1cat, float* __restrict__ b2cat,
    float* __restrict__ wd1, float* __restrict__ bd1,
    float* __restrict__ wd2, float* __restrict__ bd2) {
  int i = blockIdx.x * 256 + threadIdx.x;  // 262144
  {
    int which = i >> 16, j = i & 65535;
    float v = (which == 0) ? c1w[j] : (which == 1) ? r1w[j] : (which == 2) ? c2w[j] : r2w[j];
    unsigned short* dst = (which < 2) ? (w1cat + which * 65536) : (w2cat + (which - 2) * 65536);
    dst[j] = f2bf(v);
  }
  if (i < 32768) {
    int r = i >> 8, c = i & 255;
    wr3pad[i] = (r < 68) ? f2bf(r3w[r * 256 + c]) : (unsigned short)0;
    if (i < 128) br3pad[i] = (i < 68) ? r3b[i] : 0.f;
  }
  if (i < 256) c3wb[i] = f2bf(c3w[i]);
  if (i < 4608) {
    int tap = i >> 9, ch = i & 511, cc = ch & 255;
    wd1[i] = (ch < 256) ? d1wc[cc * 9 + tap] : d1wr[cc * 9 + tap];
    wd2[i] = (ch < 256) ? d2wc[cc * 9 + tap] : d2wr[cc * 9 + tap];
  }
  if (i < 512) {
    bd1[i] = (i < 256) ? d1bc[i] : d1br[i & 255];
    bd2[i] = (i < 256) ? d2bc[i] : d2br[i & 255];
    b1cat[i] = (i < 256) ? c1b[i] : r1b[i & 255];
    b2cat[i] = (i < 256) ? c2b[i] : r2b[i & 255];
  }
}

// ---------------- fc1 GEMM: fp32 A loaded ONCE to LDS (prologue), B dbuf --------
// Out[m,n] = bf16(X[m,:256]) . W[n,:256] + bias[n].  X fp32.
// LDS: A 64KB (all K, swizzled), B 2x8KB double-buffer.  grid = 1024*4.
// Prologue v2: slot s=j*256+tid, row=s>>5, glog=s&31 -> 32 consecutive lanes
// write 512B contiguous (conflict-free ds_write_b128), coalesced global reads.
__global__ __launch_bounds__(256, 2) void gemm_f32a(
    const float* __restrict__ X,
    const unsigned short* __restrict__ W,
    const float* __restrict__ bias,
    unsigned short* __restrict__ Out, int ldo, int lnN) {
  __shared__ unsigned short ldsA[32768];     // 128 rows x 32 granules x 8 shorts
  __shared__ unsigned short ldsB[2][4096];   // 2 x (128 rows x 4 granules x 8)
  const int nwg = gridDim.x;
  const int bid = blockIdx.x;
  const int wg = (bid & 7) * (nwg >> 3) + (bid >> 3);
  const int mtile = wg >> lnN;
  const int ntile = wg & ((1 << lnN) - 1);
  const long row0 = (long)mtile * 128;
  const int col0 = ntile * 128;

  const int tid = threadIdx.x;
  const int lane = tid & 63;
  const int wid = tid >> 6;
  const int wr = (wid >> 1) * 64;
  const int wc = (wid & 1) * 64;
  const int rr = lane & 15;
  const int gk = lane >> 4;
  const int swz = (rr >> 1) & 3;

  const int srow_l = (wid << 4) + (lane >> 2);
  const int sgl = lane & 3;

  // ---- prologue: load A fp32 -> bf16 -> swizzled LDS (once, conflict-free) ----
  #pragma unroll 4
  for (int j = 0; j < 16; j++) {
    const int s = j * 256 + tid;        // 0..4095
    const int row = s >> 5;             // 0..127
    const int glog = s & 31;            // 0..31
    const float* src = X + (row0 + row) * 256L + glog * 8;
    const float4 v0 = *(const float4*)(src);
    const float4 v1 = *(const float4*)(src + 4);
    uint4 pk;
    pk.x = cvt_pk_bf16(v0.x, v0.y);
    pk.y = cvt_pk_bf16(v0.z, v0.w);
    pk.z = cvt_pk_bf16(v1.x, v1.y);
    pk.w = cvt_pk_bf16(v1.z, v1.w);
    const int phys = (glog & ~3) | ((glog & 3) ^ ((row >> 1) & 3));
    *(uint4*)&ldsA[(row * 32 + phys) * 8] = pk;
  }

  auto stageB = [&](int buf, int k0) {
    #pragma unroll
    for (int j = 0; j < 2; j++) {
      const int slotbase = j * 256 + (wid << 6);
      const int row = j * 64 + srow_l;
      const int g = sgl ^ ((row >> 1) & 3);
      gload16(W + (long)(col0 + row) * 256 + k0 + g * 8,
              &ldsB[buf][slotbase * 8]);
    }
  };

  f32x4 acc[4][4] = {};
  stageB(0, 0);
  asm volatile("s_waitcnt vmcnt(0) lgkmcnt(0)" ::: "memory");
  __builtin_amdgcn_s_barrier();

  #pragma unroll
  for (int ks = 0; ks < 8; ks++) {
    if (ks < 7) {
      stageB((ks + 1) & 1, (ks + 1) * 32);
      asm volatile("s_waitcnt vmcnt(2)" ::: "memory");
    } else {
      asm volatile("s_waitcnt vmcnt(0)" ::: "memory");
    }
    __builtin_amdgcn_s_barrier();
    asm volatile("" ::: "memory");
    const unsigned short* bufB = ldsB[ks & 1];
    bf16x8 af[4], bf[4];
    #pragma unroll
    for (int mi = 0; mi < 4; mi++)
      af[mi] = __builtin_bit_cast(bf16x8,
          *(const uint4*)&ldsA[((wr + mi * 16 + rr) * 32 + ks * 4 + (gk ^ swz)) * 8]);
    #pragma unroll
    for (int ni = 0; ni < 4; ni++)
      bf[ni] = __builtin_bit_cast(bf16x8,
          *(const uint4*)&bufB[((wc + ni * 16 + rr) * 4 + (gk ^ swz)) * 8]);
    #pragma unroll
    for (int mi = 0; mi < 4; mi++)
      #pragma unroll
      for (int ni = 0; ni < 4; ni++)
        acc[mi][ni] = __builtin_amdgcn_mfma_f32_16x16x32_bf16(af[mi], bf[ni], acc[mi][ni], 0, 0, 0);
    asm volatile("" ::: "memory");
    __builtin_amdgcn_s_barrier();
  }

  #pragma unroll
  for (int mi = 0; mi < 4; mi++) {
    const int rbase = wr + mi * 16 + (lane >> 4) * 4;
    #pragma unroll
    for (int ni = 0; ni < 4; ni++) {
      const int c_ = wc + ni * 16 + (lane & 15);
      const float bv = bias[col0 + c_];
      #pragma unroll
      for (int r = 0; r < 4; r++) {
        Out[(row0 + rbase + r) * (long)ldo + col0 + c_] = f2bf(acc[mi][ni][r] + bv);
      }
    }
  }
}

// ---------------- GEMM: 128x128, 2-buffer, counted vmcnt(4), bounds(256,3) -------
// Out[m,n] = A[m,:256] . W[n,:256] + bias[n].
// OutF (optional): fp32 secondary output, N-cols < 68 only (fc3 reg_pred path).
__global__ __launch_bounds__(256, 3) void gemm_glds(
    const unsigned short* __restrict__ A, int lda, int zAoff,
    const unsigned short* __restrict__ W, int zWoff,
    const float* __restrict__ bias, int zBoff,
    unsigned short* __restrict__ Out, int ldo, int zOoff, int lnN,
    float* __restrict__ OutF) {
  __shared__ unsigned short lds[2][8192];   // 32 KiB: 2 bufs x (A 8KB | B 8KB)
  const int z = blockIdx.z;
  const unsigned short* Az = A + (long)z * zAoff;
  const unsigned short* Wz = W + (long)z * zWoff;
  const float* biasz = bias + z * zBoff;
  unsigned short* Outz = Out + (long)z * zOoff;

  const int nwg = gridDim.x;
  const int bid = blockIdx.x;
  const int wg = (bid & 7) * (nwg >> 3) + (bid >> 3);
  const int mtile = wg >> lnN;
  const int ntile = wg & ((1 << lnN) - 1);
  const long row0 = (long)mtile * 128;
  const int col0 = ntile * 128;

  const int tid = threadIdx.x;
  const int lane = tid & 63;
  const int wid = tid >> 6;
  const int wr = (wid >> 1) * 64;
  const int wc = (wid & 1) * 64;
  const int rr = lane & 15;
  const int gk = lane >> 4;
  const int swz = (rr >> 1) & 3;

  const int srow_l = (wid << 4) + (lane >> 2);
  const int sgl = lane & 3;

  f32x4 acc[4][4] = {};

  auto stage = [&](int buf, int k0) {
    #pragma unroll
    for (int j = 0; j < 4; j++) {
      const int slotbase = j * 256 + (wid << 6);
      unsigned short* ldst = &lds[buf][slotbase * 8];
      const int row = (j & 1) * 64 + srow_l;
      const int g = sgl ^ ((row >> 1) & 3);
      const unsigned short* src;
      if (j < 2) src = Az + (row0 + row) * (long)lda + k0 + g * 8;
      else       src = Wz + (long)(col0 + row) * 256 + k0 + g * 8;
      gload16(src, ldst);
    }
  };

  stage(0, 0);
  #pragma unroll
  for (int ks = 0; ks < 8; ks++) {
    if (ks < 7) {
      stage((ks + 1) & 1, (ks + 1) * 32);
      asm volatile("s_waitcnt vmcnt(4)" ::: "memory");
    } else {
      asm volatile("s_waitcnt vmcnt(0)" ::: "memory");
    }
    __builtin_amdgcn_s_barrier();
    asm volatile("" ::: "memory");
    const unsigned short* buf = lds[ks & 1];
    bf16x8 af[4], bf[4];
    #pragma unroll
    for (int mi = 0; mi < 4; mi++)
      af[mi] = __builtin_bit_cast(bf16x8,
          *(const uint4*)&buf[(wr + mi * 16 + rr) * 32 + ((gk ^ swz) * 8)]);
    #pragma unroll
    for (int ni = 0; ni < 4; ni++)
      bf[ni] = __builtin_bit_cast(bf16x8,
          *(const uint4*)&buf[4096 + (wc + ni * 16 + rr) * 32 + ((gk ^ swz) * 8)]);
    #pragma unroll
    for (int mi = 0; mi < 4; mi++)
      #pragma unroll
      for (int ni = 0; ni < 4; ni++)
        acc[mi][ni] = __builtin_amdgcn_mfma_f32_16x16x32_bf16(af[mi], bf[ni], acc[mi][ni], 0, 0, 0);
    asm volatile("" ::: "memory");
    __builtin_amdgcn_s_barrier();
  }

  #pragma unroll
  for (int mi = 0; mi < 4; mi++) {
    const int rbase = wr + mi * 16 + (lane >> 4) * 4;
    #pragma unroll
    for (int ni = 0; ni < 4; ni++) {
      const int c_ = wc + ni * 16 + (lane & 15);
      const float bv = biasz[col0 + c_];
      #pragma unroll
      for (int r = 0; r < 4; r++) {
        const float val = acc[mi][ni][r] + bv;
        Outz[(row0 + rbase + r) * (long)ldo + col0 + c_] = f2bf(val);
        if (OutF != nullptr && c_ < 68)
          OutF[(row0 + rbase + r) * 68L + c_] = val;
      }
    }
  }
}

// ---------------- depthwise 3x3 + bias + fast GELU, 4 pixels/thread ----------------
// CLS: lanes 0-31 (c-branch) don't store; instead compute fc3_c dot (256ch) -> cls_logit.
template <bool CLS>
__global__ __launch_bounds__(256) void dwconv_gelu4(
    const unsigned short* __restrict__ In,
    const float* __restrict__ Wt, const float* __restrict__ Bt,
    unsigned short* __restrict__ Out,
    const unsigned short* __restrict__ Wc3, const float* __restrict__ bc3,
    float* __restrict__ cls_logit) {
  const int t = blockIdx.x * 256 + threadIdx.x;  // 32768 quads * 64 groups
  const int g = t & 63;
  const int p = t >> 6;
  const int n = p >> 10;
  const int h = (p >> 4) & 63;
  const int w0 = (p & 15) << 2;
  const int cbase = g << 3;
  f32x2 acc[4][4];
  {
    float4 b0 = *(const float4*)(Bt + cbase);
    float4 b1 = *(const float4*)(Bt + cbase + 4);
    f32x2 bb[4];
    bb[0].x = b0.x; bb[0].y = b0.y; bb[1].x = b0.z; bb[1].y = b0.w;
    bb[2].x = b1.x; bb[2].y = b1.y; bb[3].x = b1.z; bb[3].y = b1.w;
    #pragma unroll
    for (int k = 0; k < 4; k++)
      #pragma unroll
      for (int i = 0; i < 4; i++) acc[k][i] = bb[i];
  }
  #pragma unroll
  for (int dy = -1; dy <= 1; dy++) {
    const int hh = h + dy;
    if (hh < 0 || hh > 63) continue;           // wave-uniform
    const float* wbase = Wt + ((dy + 1) * 3) * 512 + cbase;
    f32x2 wt[3][4];
    #pragma unroll
    for (int j = 0; j < 3; j++) {
      float4 a0 = *(const float4*)(wbase + j * 512);
      float4 a1 = *(const float4*)(wbase + j * 512 + 4);
      wt[j][0].x = a0.x; wt[j][0].y = a0.y; wt[j][1].x = a0.z; wt[j][1].y = a0.w;
      wt[j][2].x = a1.x; wt[j][2].y = a1.y; wt[j][3].x = a1.z; wt[j][3].y = a1.w;
    }
    const long rowtok = (long)(((n << 6) + hh) << 6);
    f32x2 f[6][4];
    #pragma unroll
    for (int d = 0; d < 6; d++) {
      const int col = w0 - 1 + d;
      uint4 v = {0u, 0u, 0u, 0u};
      if (col >= 0 && col < 64)                // only d=0/d=5 can fail; wave-uniform
        v = *(const uint4*)(In + (rowtok + col) * 512 + cbase);
      f[d][0] = unpack2(v.x); f[d][1] = unpack2(v.y);
      f[d][2] = unpack2(v.z); f[d][3] = unpack2(v.w);
    }
    #pragma unroll
    for (int k = 0; k < 4; k++)
      #pragma unroll
      for (int j = 0; j < 3; j++)
        #pragma unroll
        for (int i = 0; i < 4; i++)
          acc[k][i] += f[k + j][i] * wt[j][i];
  }
  f32x2 w3[4];
  if (CLS) {
    const int cc = cbase & 255;
    uint4 wv = *(const uint4*)(Wc3 + cc);
    w3[0] = unpack2(wv.x); w3[1] = unpack2(wv.y);
    w3[2] = unpack2(wv.z); w3[3] = unpack2(wv.w);
  }
  const long mbase = ((long)((n << 6) + h) << 6) + w0;
  float s[4];
  #pragma unroll
  for (int k = 0; k < 4; k++) {
    __align__(16) unsigned int ov[4];
    f32x2 ge[4];
    #pragma unroll
    for (int i = 0; i < 4; i++) {
      ge[i] = gelu2(acc[k][i]);
      ov[i] = cvt_pk_bf16(ge[i].x, ge[i].y);
    }
    if (!CLS || cbase >= 256)
      *(uint4*)(Out + (mbase + k) * 512 + cbase) = *(uint4*)ov;
    if (CLS) {
      f32x2 sp = ge[0] * w3[0] + ge[1] * w3[1] + ge[2] * w3[2] + ge[3] * w3[3];
      s[k] = sp.x + sp.y;
    }
  }
  if (CLS) {
    #pragma unroll
    for (int k = 0; k < 4; k++) {
      #pragma unroll
      for (int m = 16; m >= 1; m >>= 1) s[k] += __shfl_xor(s[k], m);
    }
    if (g == 0) {
      float b = bc3[0];
      float4 o;
      o.x = s[0] + b; o.y = s[1] + b; o.z = s[2] + b; o.w = s[3] + b;
      *(float4*)(cls_logit + mbase) = o;
    }
  }
}

// ---------------- post: softmax-17, boxes, top4, q-net, cls fuse ----------------
// out_reg is written by the fc3 GEMM; here only cls + boxes.
__global__ __launch_bounds__(256) void post_kernel(
    const unsigned short* __restrict__ RP,
    const float* __restrict__ cls_logit,
    const float* __restrict__ rc1_w, const float* __restrict__ rc1_b,
    const float* __restrict__ rc2_w, const float* __restrict__ rc2_b,
    float* __restrict__ out_cls, float* __restrict__ out_boxes) {
  int m = blockIdx.x * 256 + threadIdx.x;
  const unsigned short* rp = RP + (long)m * 128;
  __align__(16) unsigned short raw[72];
  #pragma unroll
  for (int q = 0; q < 9; q++)
    *(uint4*)(raw + q * 8) = *(const uint4*)(rp + q * 8);
  float stat[20];
  float4 boxes;
  #pragma unroll
  for (int s = 0; s < 4; s++) {
    float v[17];
    float mx = -1e30f;
    #pragma unroll
    for (int i = 0; i < 17; i++) {
      v[i] = bf2f(raw[s * 17 + i]);
      mx = fmaxf(mx, v[i]);
    }
    float sum = 0.f;
    #pragma unroll
    for (int i = 0; i < 17; i++) { v[i] = __expf(v[i] - mx); sum += v[i]; }
    float inv = 1.f / sum;
    float dist = 0.f;
    #pragma unroll
    for (int i = 0; i < 17; i++) { v[i] *= inv; dist += v[i] * (float)i; }
    ((float*)&boxes)[s] = dist * 0.0625f;
    float tk[4];
    #pragma unroll
    for (int t = 0; t < 4; t++) {
      float bm = v[0]; int bi = 0;
      #pragma unroll
      for (int i = 1; i < 17; i++) {
        if (v[i] > bm) { bm = v[i]; bi = i; }
      }
      tk[t] = bm;
      #pragma unroll
      for (int i = 0; i < 17; i++)
        if (i == bi) v[i] = -1.f;
    }
    stat[s * 5 + 0] = tk[0]; stat[s * 5 + 1] = tk[1];
    stat[s * 5 + 2] = tk[2]; stat[s * 5 + 3] = tk[3];
    stat[s * 5 + 4] = 0.25f * (tk[0] + tk[1] + tk[2] + tk[3]);
  }
  *(float4*)(out_boxes + (long)m * 4) = boxes;
  float z = 0.f;
  #pragma unroll
  for (int o = 0; o < 64; o++) {
    float q = rc1_b[o];
    #pragma unroll
    for (int c = 0; c < 20; c++) q += rc1_w[o * 20 + c] * stat[c];
    q = fmaxf(q, 0.f);
    z += q * rc2_w[o];
  }
  z += rc2_b[0];
  float q2 = 1.f / (1.f + __expf(-z));
  float cl = 1.f / (1.f + __expf(-cls_logit[m]));
  out_cls[m] = cl * q2;
}

extern "C" void kernel_launch(void* const* d_in, const int* in_sizes, int n_in,
                              void* d_out, int out_size, void* d_ws, size_t ws_size,
                              hipStream_t stream) {
  const float* x       = (const float*)d_in[0];
  const float* c_fc1_w = (const float*)d_in[1];
  const float* c_fc1_b = (const float*)d_in[2];
  const float* c_dw1_w = (const float*)d_in[3];
  const float* c_dw1_b = (const float*)d_in[4];
  const float* c_fc2_w = (const float*)d_in[5];
  const float* c_fc2_b = (const float*)d_in[6];
  const float* c_dw2_w = (const float*)d_in[7];
  const float* c_dw2_b = (const float*)d_in[8];
  const float* c_fc3_w = (const float*)d_in[9];
  const float* c_fc3_b = (const float*)d_in[10];
  const float* r_fc1_w = (const float*)d_in[11];
  const float* r_fc1_b = (const float*)d_in[12];
  const float* r_dw1_w = (const float*)d_in[13];
  const float* r_dw1_b = (const float*)d_in[14];
  const float* r_fc2_w = (const float*)d_in[15];
  const float* r_fc2_b = (const float*)d_in[16];
  const float* r_dw2_w = (const float*)d_in[17];
  const float* r_dw2_b = (const float*)d_in[18];
  const float* r_fc3_w = (const float*)d_in[19];
  const float* r_fc3_b = (const float*)d_in[20];
  const float* rc1_w   = (const float*)d_in[21];
  const float* rc1_b   = (const float*)d_in[22];
  const float* rc2_w   = (const float*)d_in[23];
  const float* rc2_b   = (const float*)d_in[24];

  char* ws = (char*)d_ws;
  unsigned short* Hbuf = (unsigned short*)ws;                       // 128 MiB
  unsigned short* Gbuf = (unsigned short*)(ws + 134217728L);        // 128 MiB
  unsigned short* RP   = (unsigned short*)(ws + 268435456L);        // 32 MiB
  float* cls_logit     = (float*)(ws + 301989888L);                 // 512 KiB
  char* wb             = ws + 302514176L;
  unsigned short* w1cat  = (unsigned short*)wb;          // 131072 bf16 (c_fc1|r_fc1)
  unsigned short* w2cat  = w1cat + 131072;               // 131072 bf16 (c_fc2|r_fc2)
  unsigned short* c3wb   = w2cat + 131072;               // 256
  unsigned short* wr3pad = c3wb + 256;                   // 32768
  float* br3pad = (float*)(wr3pad + 32768);              // 128
  float* b1cat  = br3pad + 128;                          // 512
  float* b2cat  = b1cat + 512;                           // 512
  float* wd1    = b2cat + 512;                           // 4608
  float* bd1    = wd1 + 4608;                            // 512
  float* wd2    = bd1 + 512;                             // 4608
  float* bd2    = wd2 + 4608;                            // 512

  float* out_cls   = (float*)d_out;
  float* out_boxes = out_cls + 131072;
  float* out_reg   = out_boxes + 524288;

  prep_all<<<1024, 256, 0, stream>>>(
      c_fc1_w, r_fc1_w, c_fc2_w, r_fc2_w, c_fc3_w, r_fc3_w, r_fc3_b,
      c_fc1_b, r_fc1_b, c_fc2_b, r_fc2_b,
      c_dw1_w, c_dw1_b, r_dw1_w, r_dw1_b,
      c_dw2_w, c_dw2_b, r_dw2_w, r_dw2_b,
      w1cat, w2cat, c3wb, wr3pad, br3pad, b1cat, b2cat,
      wd1, bd1, wd2, bd2);

  // fc1: A = x fp32 (prologue-staged once per block, conflict-free), N=512 (nN=4)
  gemm_f32a<<<dim3(4096, 1, 1), 256, 0, stream>>>(
      x, w1cat, b1cat, Hbuf, 512, 2);
  // dwconv1 + gelu (stores both halves)
  dwconv_gelu4<false><<<8192, 256, 0, stream>>>(Hbuf, wd1, bd1, Gbuf,
                                                nullptr, nullptr, nullptr);
  // fc2: branches via z (nN=2 per branch)
  gemm_glds<<<dim3(2048, 1, 2), 256, 0, stream>>>(
      Gbuf, 512, 256, w2cat, 65536, b2cat, 256, Hbuf, 512, 256, 1, nullptr);
  // dwconv2 + gelu + fused cls dot (stores only r-half)
  dwconv_gelu4<true><<<8192, 256, 0, stream>>>(Hbuf, wd2, bd2, Gbuf,
                                               c3wb, c_fc3_b, cls_logit);
  // fc3 (r-half): bf16 RP for post + fp32 out_reg directly
  gemm_glds<<<dim3(1024, 1, 1), 256, 0, stream>>>(
      Gbuf + 256, 512, 0, wr3pad, 0, br3pad, 0, RP, 128, 0, 0, out_reg);
  // post (cls + boxes only)
  post_kernel<<<512, 256, 0, stream>>>(RP, cls_logit, rc1_w, rc1_b, rc2_w, rc2_b,
                                       out_cls, out_boxes);
}

// Round 18
// 363.725 us; speedup vs baseline: 1.0806x; 1.0081x over previous
//
#include <hip/hip_runtime.h>
#include <hip/hip_bf16.h>

typedef __bf16 bf16x8 __attribute__((ext_vector_type(8)));
typedef float f32x4 __attribute__((ext_vector_type(4)));
typedef float f32x2 __attribute__((ext_vector_type(2)));

__device__ __forceinline__ float bf2f(unsigned short b) {
  unsigned int u = ((unsigned int)b) << 16;
  return __builtin_bit_cast(float, u);
}
__device__ __forceinline__ unsigned short f2bf(float f) {
  unsigned int u = __builtin_bit_cast(unsigned int, f);
  unsigned int r = u + 0x7fffu + ((u >> 16) & 1u);
  return (unsigned short)(r >> 16);
}
__device__ __forceinline__ f32x2 unpack2(unsigned int u) {
  f32x2 r;
  r.x = __builtin_bit_cast(float, u << 16);
  r.y = __builtin_bit_cast(float, u & 0xffff0000u);
  return r;
}

__device__ __forceinline__ void gload16(const void* g, void* l) {
  typedef __attribute__((address_space(1))) const void* gp_t;
  typedef __attribute__((address_space(3))) void* lp_t;
  __builtin_amdgcn_global_load_lds((gp_t)g, (lp_t)l, 16, 0, 0);
}

// fast GELU: x * sigmoid(1.5958(x + 0.044715 x^3)), |err vs exact erf| <= ~5e-4.
__device__ __forceinline__ f32x2 gelu2(f32x2 x) {
  f32x2 m = x * x;
  f32x2 t = m * (-0.10295273f) + (-2.3021967f);
  f32x2 u = x * t;
  f32x2 e;
  e.x = __builtin_amdgcn_exp2f(u.x);
  e.y = __builtin_amdgcn_exp2f(u.y);
  f32x2 d = e + 1.0f;
  f32x2 r;
  r.x = __builtin_amdgcn_rcpf(d.x);
  r.y = __builtin_amdgcn_rcpf(d.y);
  return x * r;
}
__device__ __forceinline__ unsigned int cvt_pk_bf16(float lo, float hi) {
  unsigned int r;
  asm("v_cvt_pk_bf16_f32 %0, %1, %2" : "=v"(r) : "v"(lo), "v"(hi));
  return r;
}

// ---------------- fused weight prep (one dispatch) ----------------
__global__ __launch_bounds__(256) void prep_all(
    const float* __restrict__ c1w, const float* __restrict__ r1w,
    const float* __restrict__ c2w, const float* __restrict__ r2w,
    const float* __restrict__ c3w, const float* __restrict__ r3w, const float* __restrict__ r3b,
    const float* __restrict__ c1b, const float* __restrict__ r1b,
    const float* __restrict__ c2b, const float* __restrict__ r2b,
    const float* __restrict__ d1wc, const float* __restrict__ d1bc,
    const float* __restrict__ d1wr, const float* __restrict__ d1br,
    const float* __restrict__ d2wc, const float* __restrict__ d2bc,
    const float* __restrict__ d2wr, const float* __restrict__ d2br,
    unsigned short* __restrict__ w1cat, unsigned short* __restrict__ w2cat,
    unsigned short* __restrict__ c3wb, unsigned short* __restrict__ wr3pad,
    float* __restrict__ br3pad, float* __restrict__ b1cat, float* __restrict__ b2cat,
    float* __restrict__ wd1, float* __restrict__ bd1,
    float* __restrict__ wd2, float* __restrict__ bd2) {
  int i = blockIdx.x * 256 + threadIdx.x;  // 262144
  {
    int which = i >> 16, j = i & 65535;
    float v = (which == 0) ? c1w[j] : (which == 1) ? r1w[j] : (which == 2) ? c2w[j] : r2w[j];
    unsigned short* dst = (which < 2) ? (w1cat + which * 65536) : (w2cat + (which - 2) * 65536);
    dst[j] = f2bf(v);
  }
  if (i < 32768) {
    int r = i >> 8, c = i & 255;
    wr3pad[i] = (r < 68) ? f2bf(r3w[r * 256 + c]) : (unsigned short)0;
    if (i < 128) br3pad[i] = (i < 68) ? r3b[i] : 0.f;
  }
  if (i < 256) c3wb[i] = f2bf(c3w[i]);
  if (i < 4608) {
    int tap = i >> 9, ch = i & 511, cc = ch & 255;
    wd1[i] = (ch < 256) ? d1wc[cc * 9 + tap] : d1wr[cc * 9 + tap];
    wd2[i] = (ch < 256) ? d2wc[cc * 9 + tap] : d2wr[cc * 9 + tap];
  }
  if (i < 512) {
    bd1[i] = (i < 256) ? d1bc[i] : d1br[i & 255];
    bd2[i] = (i < 256) ? d2bc[i] : d2br[i & 255];
    b1cat[i] = (i < 256) ? c1b[i] : r1b[i & 255];
    b2cat[i] = (i < 256) ? c2b[i] : r2b[i & 255];
  }
}

// ---------------- fc1 GEMM: fp32 A loaded ONCE to LDS (prologue), B dbuf --------
// Out[m,n] = bf16(X[m,:256]) . W[n,:256] + bias[n].  X fp32.
// ldsA row-stride 512B -> full 3-bit XOR swizzle: phys = glog ^ (row & 7)
// (write: per-row permutation, conflict-free; read: 16 rows @ fixed glog ->
// 8 distinct bank-groups = 2-way = free).  B path unchanged (gload_lds).
__global__ __launch_bounds__(256, 2) void gemm_f32a(
    const float* __restrict__ X,
    const unsigned short* __restrict__ W,
    const float* __restrict__ bias,
    unsigned short* __restrict__ Out, int ldo, int lnN) {
  __shared__ unsigned short ldsA[32768];     // 128 rows x 32 granules x 8 shorts
  __shared__ unsigned short ldsB[2][4096];   // 2 x (128 rows x 4 granules x 8)
  const int nwg = gridDim.x;
  const int bid = blockIdx.x;
  const int wg = (bid & 7) * (nwg >> 3) + (bid >> 3);
  const int mtile = wg >> lnN;
  const int ntile = wg & ((1 << lnN) - 1);
  const long row0 = (long)mtile * 128;
  const int col0 = ntile * 128;

  const int tid = threadIdx.x;
  const int lane = tid & 63;
  const int wid = tid >> 6;
  const int wr = (wid >> 1) * 64;
  const int wc = (wid & 1) * 64;
  const int rr = lane & 15;
  const int gk = lane >> 4;
  const int swz = (rr >> 1) & 3;

  const int srow_l = (wid << 4) + (lane >> 2);
  const int sgl = lane & 3;

  // ---- prologue: load A fp32 -> bf16 -> XOR-swizzled LDS (once) ----
  #pragma unroll 4
  for (int j = 0; j < 16; j++) {
    const int s = j * 256 + tid;        // 0..4095
    const int row = s >> 5;             // 0..127
    const int glog = s & 31;            // 0..31
    const float* src = X + (row0 + row) * 256L + glog * 8;
    const float4 v0 = *(const float4*)(src);
    const float4 v1 = *(const float4*)(src + 4);
    uint4 pk;
    pk.x = cvt_pk_bf16(v0.x, v0.y);
    pk.y = cvt_pk_bf16(v0.z, v0.w);
    pk.z = cvt_pk_bf16(v1.x, v1.y);
    pk.w = cvt_pk_bf16(v1.z, v1.w);
    const int phys = glog ^ (row & 7);
    *(uint4*)&ldsA[(row * 32 + phys) * 8] = pk;
  }

  auto stageB = [&](int buf, int k0) {
    #pragma unroll
    for (int j = 0; j < 2; j++) {
      const int slotbase = j * 256 + (wid << 6);
      const int row = j * 64 + srow_l;
      const int g = sgl ^ ((row >> 1) & 3);
      gload16(W + (long)(col0 + row) * 256 + k0 + g * 8,
              &ldsB[buf][slotbase * 8]);
    }
  };

  f32x4 acc[4][4] = {};
  stageB(0, 0);
  asm volatile("s_waitcnt vmcnt(0) lgkmcnt(0)" ::: "memory");
  __builtin_amdgcn_s_barrier();

  #pragma unroll
  for (int ks = 0; ks < 8; ks++) {
    if (ks < 7) {
      stageB((ks + 1) & 1, (ks + 1) * 32);
      asm volatile("s_waitcnt vmcnt(2)" ::: "memory");
    } else {
      asm volatile("s_waitcnt vmcnt(0)" ::: "memory");
    }
    __builtin_amdgcn_s_barrier();
    asm volatile("" ::: "memory");
    const unsigned short* bufB = ldsB[ks & 1];
    bf16x8 af[4], bf[4];
    #pragma unroll
    for (int mi = 0; mi < 4; mi++) {
      const int arow = wr + mi * 16 + rr;
      const int aphys = (ks * 4 + gk) ^ (arow & 7);
      af[mi] = __builtin_bit_cast(bf16x8,
          *(const uint4*)&ldsA[(arow * 32 + aphys) * 8]);
    }
    #pragma unroll
    for (int ni = 0; ni < 4; ni++)
      bf[ni] = __builtin_bit_cast(bf16x8,
          *(const uint4*)&bufB[((wc + ni * 16 + rr) * 4 + (gk ^ swz)) * 8]);
    #pragma unroll
    for (int mi = 0; mi < 4; mi++)
      #pragma unroll
      for (int ni = 0; ni < 4; ni++)
        acc[mi][ni] = __builtin_amdgcn_mfma_f32_16x16x32_bf16(af[mi], bf[ni], acc[mi][ni], 0, 0, 0);
    asm volatile("" ::: "memory");
    __builtin_amdgcn_s_barrier();
  }

  #pragma unroll
  for (int mi = 0; mi < 4; mi++) {
    const int rbase = wr + mi * 16 + (lane >> 4) * 4;
    #pragma unroll
    for (int ni = 0; ni < 4; ni++) {
      const int c_ = wc + ni * 16 + (lane & 15);
      const float bv = bias[col0 + c_];
      #pragma unroll
      for (int r = 0; r < 4; r++) {
        Out[(row0 + rbase + r) * (long)ldo + col0 + c_] = f2bf(acc[mi][ni][r] + bv);
      }
    }
  }
}

// ---------------- GEMM: 128x128, 2-buffer, counted vmcnt(4), bounds(256,3) -------
// Out[m,n] = A[m,:256] . W[n,:256] + bias[n].
// OutF (optional): fp32 secondary output, N-cols < 68 only (fc3 reg_pred path).
__global__ __launch_bounds__(256, 3) void gemm_glds(
    const unsigned short* __restrict__ A, int lda, int zAoff,
    const unsigned short* __restrict__ W, int zWoff,
    const float* __restrict__ bias, int zBoff,
    unsigned short* __restrict__ Out, int ldo, int zOoff, int lnN,
    float* __restrict__ OutF) {
  __shared__ unsigned short lds[2][8192];   // 32 KiB: 2 bufs x (A 8KB | B 8KB)
  const int z = blockIdx.z;
  const unsigned short* Az = A + (long)z * zAoff;
  const unsigned short* Wz = W + (long)z * zWoff;
  const float* biasz = bias + z * zBoff;
  unsigned short* Outz = Out + (long)z * zOoff;

  const int nwg = gridDim.x;
  const int bid = blockIdx.x;
  const int wg = (bid & 7) * (nwg >> 3) + (bid >> 3);
  const int mtile = wg >> lnN;
  const int ntile = wg & ((1 << lnN) - 1);
  const long row0 = (long)mtile * 128;
  const int col0 = ntile * 128;

  const int tid = threadIdx.x;
  const int lane = tid & 63;
  const int wid = tid >> 6;
  const int wr = (wid >> 1) * 64;
  const int wc = (wid & 1) * 64;
  const int rr = lane & 15;
  const int gk = lane >> 4;
  const int swz = (rr >> 1) & 3;

  const int srow_l = (wid << 4) + (lane >> 2);
  const int sgl = lane & 3;

  f32x4 acc[4][4] = {};

  auto stage = [&](int buf, int k0) {
    #pragma unroll
    for (int j = 0; j < 4; j++) {
      const int slotbase = j * 256 + (wid << 6);
      unsigned short* ldst = &lds[buf][slotbase * 8];
      const int row = (j & 1) * 64 + srow_l;
      const int g = sgl ^ ((row >> 1) & 3);
      const unsigned short* src;
      if (j < 2) src = Az + (row0 + row) * (long)lda + k0 + g * 8;
      else       src = Wz + (long)(col0 + row) * 256 + k0 + g * 8;
      gload16(src, ldst);
    }
  };

  stage(0, 0);
  #pragma unroll
  for (int ks = 0; ks < 8; ks++) {
    if (ks < 7) {
      stage((ks + 1) & 1, (ks + 1) * 32);
      asm volatile("s_waitcnt vmcnt(4)" ::: "memory");
    } else {
      asm volatile("s_waitcnt vmcnt(0)" ::: "memory");
    }
    __builtin_amdgcn_s_barrier();
    asm volatile("" ::: "memory");
    const unsigned short* buf = lds[ks & 1];
    bf16x8 af[4], bf[4];
    #pragma unroll
    for (int mi = 0; mi < 4; mi++)
      af[mi] = __builtin_bit_cast(bf16x8,
          *(const uint4*)&buf[(wr + mi * 16 + rr) * 32 + ((gk ^ swz) * 8)]);
    #pragma unroll
    for (int ni = 0; ni < 4; ni++)
      bf[ni] = __builtin_bit_cast(bf16x8,
          *(const uint4*)&buf[4096 + (wc + ni * 16 + rr) * 32 + ((gk ^ swz) * 8)]);
    #pragma unroll
    for (int mi = 0; mi < 4; mi++)
      #pragma unroll
      for (int ni = 0; ni < 4; ni++)
        acc[mi][ni] = __builtin_amdgcn_mfma_f32_16x16x32_bf16(af[mi], bf[ni], acc[mi][ni], 0, 0, 0);
    asm volatile("" ::: "memory");
    __builtin_amdgcn_s_barrier();
  }

  #pragma unroll
  for (int mi = 0; mi < 4; mi++) {
    const int rbase = wr + mi * 16 + (lane >> 4) * 4;
    #pragma unroll
    for (int ni = 0; ni < 4; ni++) {
      const int c_ = wc + ni * 16 + (lane & 15);
      const float bv = biasz[col0 + c_];
      #pragma unroll
      for (int r = 0; r < 4; r++) {
        const float val = acc[mi][ni][r] + bv;
        Outz[(row0 + rbase + r) * (long)ldo + col0 + c_] = f2bf(val);
        if (OutF != nullptr && c_ < 68)
          OutF[(row0 + rbase + r) * 68L + c_] = val;
      }
    }
  }
}

// ---------------- depthwise 3x3 + bias + fast GELU, 4 pixels/thread ----------------
// CLS: lanes 0-31 (c-branch) don't store; instead compute fc3_c dot (256ch) -> cls_logit.
template <bool CLS>
__global__ __launch_bounds__(256) void dwconv_gelu4(
    const unsigned short* __restrict__ In,
    const float* __restrict__ Wt, const float* __restrict__ Bt,
    unsigned short* __restrict__ Out,
    const unsigned short* __restrict__ Wc3, const float* __restrict__ bc3,
    float* __restrict__ cls_logit) {
  const int t = blockIdx.x * 256 + threadIdx.x;  // 32768 quads * 64 groups
  const int g = t & 63;
  const int p = t >> 6;
  const int n = p >> 10;
  const int h = (p >> 4) & 63;
  const int w0 = (p & 15) << 2;
  const int cbase = g << 3;
  f32x2 acc[4][4];
  {
    float4 b0 = *(const float4*)(Bt + cbase);
    float4 b1 = *(const float4*)(Bt + cbase + 4);
    f32x2 bb[4];
    bb[0].x = b0.x; bb[0].y = b0.y; bb[1].x = b0.z; bb[1].y = b0.w;
    bb[2].x = b1.x; bb[2].y = b1.y; bb[3].x = b1.z; bb[3].y = b1.w;
    #pragma unroll
    for (int k = 0; k < 4; k++)
      #pragma unroll
      for (int i = 0; i < 4; i++) acc[k][i] = bb[i];
  }
  #pragma unroll
  for (int dy = -1; dy <= 1; dy++) {
    const int hh = h + dy;
    if (hh < 0 || hh > 63) continue;           // wave-uniform
    const float* wbase = Wt + ((dy + 1) * 3) * 512 + cbase;
    f32x2 wt[3][4];
    #pragma unroll
    for (int j = 0; j < 3; j++) {
      float4 a0 = *(const float4*)(wbase + j * 512);
      float4 a1 = *(const float4*)(wbase + j * 512 + 4);
      wt[j][0].x = a0.x; wt[j][0].y = a0.y; wt[j][1].x = a0.z; wt[j][1].y = a0.w;
      wt[j][2].x = a1.x; wt[j][2].y = a1.y; wt[j][3].x = a1.z; wt[j][3].y = a1.w;
    }
    const long rowtok = (long)(((n << 6) + hh) << 6);
    f32x2 f[6][4];
    #pragma unroll
    for (int d = 0; d < 6; d++) {
      const int col = w0 - 1 + d;
      uint4 v = {0u, 0u, 0u, 0u};
      if (col >= 0 && col < 64)                // only d=0/d=5 can fail; wave-uniform
        v = *(const uint4*)(In + (rowtok + col) * 512 + cbase);
      f[d][0] = unpack2(v.x); f[d][1] = unpack2(v.y);
      f[d][2] = unpack2(v.z); f[d][3] = unpack2(v.w);
    }
    #pragma unroll
    for (int k = 0; k < 4; k++)
      #pragma unroll
      for (int j = 0; j < 3; j++)
        #pragma unroll
        for (int i = 0; i < 4; i++)
          acc[k][i] += f[k + j][i] * wt[j][i];
  }
  f32x2 w3[4];
  if (CLS) {
    const int cc = cbase & 255;
    uint4 wv = *(const uint4*)(Wc3 + cc);
    w3[0] = unpack2(wv.x); w3[1] = unpack2(wv.y);
    w3[2] = unpack2(wv.z); w3[3] = unpack2(wv.w);
  }
  const long mbase = ((long)((n << 6) + h) << 6) + w0;
  float s[4];
  #pragma unroll
  for (int k = 0; k < 4; k++) {
    __align__(16) unsigned int ov[4];
    f32x2 ge[4];
    #pragma unroll
    for (int i = 0; i < 4; i++) {
      ge[i] = gelu2(acc[k][i]);
      ov[i] = cvt_pk_bf16(ge[i].x, ge[i].y);
    }
    if (!CLS || cbase >= 256)
      *(uint4*)(Out + (mbase + k) * 512 + cbase) = *(uint4*)ov;
    if (CLS) {
      f32x2 sp = ge[0] * w3[0] + ge[1] * w3[1] + ge[2] * w3[2] + ge[3] * w3[3];
      s[k] = sp.x + sp.y;
    }
  }
  if (CLS) {
    #pragma unroll
    for (int k = 0; k < 4; k++) {
      #pragma unroll
      for (int m = 16; m >= 1; m >>= 1) s[k] += __shfl_xor(s[k], m);
    }
    if (g == 0) {
      float b = bc3[0];
      float4 o;
      o.x = s[0] + b; o.y = s[1] + b; o.z = s[2] + b; o.w = s[3] + b;
      *(float4*)(cls_logit + mbase) = o;
    }
  }
}

// ---------------- post: softmax-17, boxes, top4, q-net, cls fuse ----------------
// out_reg is written by the fc3 GEMM; here only cls + boxes.
__global__ __launch_bounds__(256) void post_kernel(
    const unsigned short* __restrict__ RP,
    const float* __restrict__ cls_logit,
    const float* __restrict__ rc1_w, const float* __restrict__ rc1_b,
    const float* __restrict__ rc2_w, const float* __restrict__ rc2_b,
    float* __restrict__ out_cls, float* __restrict__ out_boxes) {
  int m = blockIdx.x * 256 + threadIdx.x;
  const unsigned short* rp = RP + (long)m * 128;
  __align__(16) unsigned short raw[72];
  #pragma unroll
  for (int q = 0; q < 9; q++)
    *(uint4*)(raw + q * 8) = *(const uint4*)(rp + q * 8);
  float stat[20];
  float4 boxes;
  #pragma unroll
  for (int s = 0; s < 4; s++) {
    float v[17];
    float mx = -1e30f;
    #pragma unroll
    for (int i = 0; i < 17; i++) {
      v[i] = bf2f(raw[s * 17 + i]);
      mx = fmaxf(mx, v[i]);
    }
    float sum = 0.f;
    #pragma unroll
    for (int i = 0; i < 17; i++) { v[i] = __expf(v[i] - mx); sum += v[i]; }
    float inv = 1.f / sum;
    float dist = 0.f;
    #pragma unroll
    for (int i = 0; i < 17; i++) { v[i] *= inv; dist += v[i] * (float)i; }
    ((float*)&boxes)[s] = dist * 0.0625f;
    float tk[4];
    #pragma unroll
    for (int t = 0; t < 4; t++) {
      float bm = v[0]; int bi = 0;
      #pragma unroll
      for (int i = 1; i < 17; i++) {
        if (v[i] > bm) { bm = v[i]; bi = i; }
      }
      tk[t] = bm;
      #pragma unroll
      for (int i = 0; i < 17; i++)
        if (i == bi) v[i] = -1.f;
    }
    stat[s * 5 + 0] = tk[0]; stat[s * 5 + 1] = tk[1];
    stat[s * 5 + 2] = tk[2]; stat[s * 5 + 3] = tk[3];
    stat[s * 5 + 4] = 0.25f * (tk[0] + tk[1] + tk[2] + tk[3]);
  }
  *(float4*)(out_boxes + (long)m * 4) = boxes;
  float z = 0.f;
  #pragma unroll
  for (int o = 0; o < 64; o++) {
    float q = rc1_b[o];
    #pragma unroll
    for (int c = 0; c < 20; c++) q += rc1_w[o * 20 + c] * stat[c];
    q = fmaxf(q, 0.f);
    z += q * rc2_w[o];
  }
  z += rc2_b[0];
  float q2 = 1.f / (1.f + __expf(-z));
  float cl = 1.f / (1.f + __expf(-cls_logit[m]));
  out_cls[m] = cl * q2;
}

extern "C" void kernel_launch(void* const* d_in, const int* in_sizes, int n_in,
                              void* d_out, int out_size, void* d_ws, size_t ws_size,
                              hipStream_t stream) {
  const float* x       = (const float*)d_in[0];
  const float* c_fc1_w = (const float*)d_in[1];
  const float* c_fc1_b = (const float*)d_in[2];
  const float* c_dw1_w = (const float*)d_in[3];
  const float* c_dw1_b = (const float*)d_in[4];
  const float* c_fc2_w = (const float*)d_in[5];
  const float* c_fc2_b = (const float*)d_in[6];
  const float* c_dw2_w = (const float*)d_in[7];
  const float* c_dw2_b = (const float*)d_in[8];
  const float* c_fc3_w = (const float*)d_in[9];
  const float* c_fc3_b = (const float*)d_in[10];
  const float* r_fc1_w = (const float*)d_in[11];
  const float* r_fc1_b = (const float*)d_in[12];
  const float* r_dw1_w = (const float*)d_in[13];
  const float* r_dw1_b = (const float*)d_in[14];
  const float* r_fc2_w = (const float*)d_in[15];
  const float* r_fc2_b = (const float*)d_in[16];
  const float* r_dw2_w = (const float*)d_in[17];
  const float* r_dw2_b = (const float*)d_in[18];
  const float* r_fc3_w = (const float*)d_in[19];
  const float* r_fc3_b = (const float*)d_in[20];
  const float* rc1_w   = (const float*)d_in[21];
  const float* rc1_b   = (const float*)d_in[22];
  const float* rc2_w   = (const float*)d_in[23];
  const float* rc2_b   = (const float*)d_in[24];

  char* ws = (char*)d_ws;
  unsigned short* Hbuf = (unsigned short*)ws;                       // 128 MiB
  unsigned short* Gbuf = (unsigned short*)(ws + 134217728L);        // 128 MiB
  unsigned short* RP   = (unsigned short*)(ws + 268435456L);        // 32 MiB
  float* cls_logit     = (float*)(ws + 301989888L);                 // 512 KiB
  char* wb             = ws + 302514176L;
  unsigned short* w1cat  = (unsigned short*)wb;          // 131072 bf16 (c_fc1|r_fc1)
  unsigned short* w2cat  = w1cat + 131072;               // 131072 bf16 (c_fc2|r_fc2)
  unsigned short* c3wb   = w2cat + 131072;               // 256
  unsigned short* wr3pad = c3wb + 256;                   // 32768
  float* br3pad = (float*)(wr3pad + 32768);              // 128
  float* b1cat  = br3pad + 128;                          // 512
  float* b2cat  = b1cat + 512;                           // 512
  float* wd1    = b2cat + 512;                           // 4608
  float* bd1    = wd1 + 4608;                            // 512
  float* wd2    = bd1 + 512;                             // 4608
  float* bd2    = wd2 + 4608;                            // 512

  float* out_cls   = (float*)d_out;
  float* out_boxes = out_cls + 131072;
  float* out_reg   = out_boxes + 524288;

  prep_all<<<1024, 256, 0, stream>>>(
      c_fc1_w, r_fc1_w, c_fc2_w, r_fc2_w, c_fc3_w, r_fc3_w, r_fc3_b,
      c_fc1_b, r_fc1_b, c_fc2_b, r_fc2_b,
      c_dw1_w, c_dw1_b, r_dw1_w, r_dw1_b,
      c_dw2_w, c_dw2_b, r_dw2_w, r_dw2_b,
      w1cat, w2cat, c3wb, wr3pad, br3pad, b1cat, b2cat,
      wd1, bd1, wd2, bd2);

  // fc1: A = x fp32 (prologue-staged once per block, full XOR swizzle), N=512 (nN=4)
  gemm_f32a<<<dim3(4096, 1, 1), 256, 0, stream>>>(
      x, w1cat, b1cat, Hbuf, 512, 2);
  // dwconv1 + gelu (stores both halves)
  dwconv_gelu4<false><<<8192, 256, 0, stream>>>(Hbuf, wd1, bd1, Gbuf,
                                                nullptr, nullptr, nullptr);
  // fc2: branches via z (nN=2 per branch)
  gemm_glds<<<dim3(2048, 1, 2), 256, 0, stream>>>(
      Gbuf, 512, 256, w2cat, 65536, b2cat, 256, Hbuf, 512, 256, 1, nullptr);
  // dwconv2 + gelu + fused cls dot (stores only r-half)
  dwconv_gelu4<true><<<8192, 256, 0, stream>>>(Hbuf, wd2, bd2, Gbuf,
                                               c3wb, c_fc3_b, cls_logit);
  // fc3 (r-half): bf16 RP for post + fp32 out_reg directly
  gemm_glds<<<dim3(1024, 1, 1), 256, 0, stream>>>(
      Gbuf + 256, 512, 0, wr3pad, 0, br3pad, 0, RP, 128, 0, 0, out_reg);
  // post (cls + boxes only)
  post_kernel<<<512, 256, 0, stream>>>(RP, cls_logit, rc1_w, rc1_b, rc2_w, rc2_b,
                                       out_cls, out_boxes);
}

// Round 19
// 361.389 us; speedup vs baseline: 1.0876x; 1.0065x over previous
//
#include <hip/hip_runtime.h>
#include <hip/hip_bf16.h>

typedef __bf16 bf16x8 __attribute__((ext_vector_type(8)));
typedef float f32x4 __attribute__((ext_vector_type(4)));
typedef float f32x2 __attribute__((ext_vector_type(2)));

__device__ __forceinline__ float bf2f(unsigned short b) {
  unsigned int u = ((unsigned int)b) << 16;
  return __builtin_bit_cast(float, u);
}
__device__ __forceinline__ unsigned short f2bf(float f) {
  unsigned int u = __builtin_bit_cast(unsigned int, f);
  unsigned int r = u + 0x7fffu + ((u >> 16) & 1u);
  return (unsigned short)(r >> 16);
}
__device__ __forceinline__ f32x2 unpack2(unsigned int u) {
  f32x2 r;
  r.x = __builtin_bit_cast(float, u << 16);
  r.y = __builtin_bit_cast(float, u & 0xffff0000u);
  return r;
}

__device__ __forceinline__ void gload16(const void* g, void* l) {
  typedef __attribute__((address_space(1))) const void* gp_t;
  typedef __attribute__((address_space(3))) void* lp_t;
  __builtin_amdgcn_global_load_lds((gp_t)g, (lp_t)l, 16, 0, 0);
}

// fast GELU: x * sigmoid(1.5958(x + 0.044715 x^3)), |err vs exact erf| <= ~5e-4.
__device__ __forceinline__ f32x2 gelu2(f32x2 x) {
  f32x2 m = x * x;
  f32x2 t = m * (-0.10295273f) + (-2.3021967f);
  f32x2 u = x * t;
  f32x2 e;
  e.x = __builtin_amdgcn_exp2f(u.x);
  e.y = __builtin_amdgcn_exp2f(u.y);
  f32x2 d = e + 1.0f;
  f32x2 r;
  r.x = __builtin_amdgcn_rcpf(d.x);
  r.y = __builtin_amdgcn_rcpf(d.y);
  return x * r;
}
__device__ __forceinline__ unsigned int cvt_pk_bf16(float lo, float hi) {
  unsigned int r;
  asm("v_cvt_pk_bf16_f32 %0, %1, %2" : "=v"(r) : "v"(lo), "v"(hi));
  return r;
}

// ---------------- fused weight prep (one dispatch) ----------------
__global__ __launch_bounds__(256) void prep_all(
    const float* __restrict__ c1w, const float* __restrict__ r1w,
    const float* __restrict__ c2w, const float* __restrict__ r2w,
    const float* __restrict__ c3w, const float* __restrict__ r3w, const float* __restrict__ r3b,
    const float* __restrict__ c1b, const float* __restrict__ r1b,
    const float* __restrict__ c2b, const float* __restrict__ r2b,
    const float* __restrict__ d1wc, const float* __restrict__ d1bc,
    const float* __restrict__ d1wr, const float* __restrict__ d1br,
    const float* __restrict__ d2wc, const float* __restrict__ d2bc,
    const float* __restrict__ d2wr, const float* __restrict__ d2br,
    unsigned short* __restrict__ w1cat, unsigned short* __restrict__ w2cat,
    unsigned short* __restrict__ c3wb, unsigned short* __restrict__ wr3pad,
    float* __restrict__ br3pad, float* __restrict__ b1cat, float* __restrict__ b2cat,
    float* __restrict__ wd1, float* __restrict__ bd1,
    float* __restrict__ wd2, float* __restrict__ bd2) {
  int i = blockIdx.x * 256 + threadIdx.x;  // 262144
  {
    int which = i >> 16, j = i & 65535;
    float v = (which == 0) ? c1w[j] : (which == 1) ? r1w[j] : (which == 2) ? c2w[j] : r2w[j];
    unsigned short* dst = (which < 2) ? (w1cat + which * 65536) : (w2cat + (which - 2) * 65536);
    dst[j] = f2bf(v);
  }
  if (i < 32768) {
    int r = i >> 8, c = i & 255;
    wr3pad[i] = (r < 68) ? f2bf(r3w[r * 256 + c]) : (unsigned short)0;
    if (i < 128) br3pad[i] = (i < 68) ? r3b[i] : 0.f;
  }
  if (i < 256) c3wb[i] = f2bf(c3w[i]);
  if (i < 4608) {
    int tap = i >> 9, ch = i & 511, cc = ch & 255;
    wd1[i] = (ch < 256) ? d1wc[cc * 9 + tap] : d1wr[cc * 9 + tap];
    wd2[i] = (ch < 256) ? d2wc[cc * 9 + tap] : d2wr[cc * 9 + tap];
  }
  if (i < 512) {
    bd1[i] = (i < 256) ? d1bc[i] : d1br[i & 255];
    bd2[i] = (i < 256) ? d2bc[i] : d2br[i & 255];
    b1cat[i] = (i < 256) ? c1b[i] : r1b[i & 255];
    b2cat[i] = (i < 256) ? c2b[i] : r2b[i & 255];
  }
}

// ---------------- fc1 GEMM: A fp32 staged per-K-step via global_load_lds -------
// Out[m,n] = bf16(X[m,:256]) . W[n,:256] + bias[n].  X fp32, converted to bf16
// IN REGISTER after the LDS read (16 v_cvt_pk per K-step).  Per K-step stage:
// A = 16KB fp32 (4 wave-gloads, source-swizzled gl = gp ^ (row&7)), B = 8KB bf16.
// LDS 48KB total -> 3 blocks/CU.  No prologue, no manual ds_write, no cvt_x pass.
__global__ __launch_bounds__(256, 3) void gemm_xa(
    const float* __restrict__ X,
    const unsigned short* __restrict__ W,
    const float* __restrict__ bias,
    unsigned short* __restrict__ Out, int ldo, int lnN) {
  __shared__ float ldsA[2][4096];            // 2 x 16KB: 128 rows x 8 granules x 4 f32
  __shared__ unsigned short ldsB[2][4096];   // 2 x 8KB:  128 rows x 4 granules x 8 bf16
  const int nwg = gridDim.x;
  const int bid = blockIdx.x;
  const int wg = (bid & 7) * (nwg >> 3) + (bid >> 3);
  const int mtile = wg >> lnN;
  const int ntile = wg & ((1 << lnN) - 1);
  const long row0 = (long)mtile * 128;
  const int col0 = ntile * 128;

  const int tid = threadIdx.x;
  const int lane = tid & 63;
  const int wid = tid >> 6;
  const int wr = (wid >> 1) * 64;
  const int wc = (wid & 1) * 64;
  const int rr = lane & 15;
  const int gk = lane >> 4;              // k-granule-pair selector 0..3
  const int swz = (rr >> 1) & 3;

  const int srow_l = (wid << 4) + (lane >> 2);
  const int sgl = lane & 3;

  // A staging: slot s = j*256 + wid*64 + lane; row = s>>3, phys granule = s&7;
  // source column = (s&7) ^ (row&7)  (per-lane global addr; LDS dest linear).
  const int sA_base = (wid << 6);
  const int sA_row_l = lane >> 3;        // within-wave row 0..7
  const int sA_gp = lane & 7;

  auto stageA = [&](int buf, int k0) {
    #pragma unroll
    for (int j = 0; j < 4; j++) {
      const int gran_base = j * 256 + sA_base;          // wave-uniform
      const int row = (gran_base >> 3) + sA_row_l;      // per-lane
      const int gl = sA_gp ^ (row & 7);
      gload16(X + (row0 + row) * 256L + k0 + gl * 4,
              &ldsA[buf][gran_base * 4]);
    }
  };
  auto stageB = [&](int buf, int k0) {
    #pragma unroll
    for (int j = 0; j < 2; j++) {
      const int slotbase = j * 256 + (wid << 6);
      const int row = j * 64 + srow_l;
      const int g = sgl ^ ((row >> 1) & 3);
      gload16(W + (long)(col0 + row) * 256 + k0 + g * 8,
              &ldsB[buf][slotbase * 8]);
    }
  };

  f32x4 acc[4][4] = {};
  stageA(0, 0);
  stageB(0, 0);
  #pragma unroll
  for (int ks = 0; ks < 8; ks++) {
    if (ks < 7) {
      stageA((ks + 1) & 1, (ks + 1) * 32);
      stageB((ks + 1) & 1, (ks + 1) * 32);
      asm volatile("s_waitcnt vmcnt(6)" ::: "memory");
    } else {
      asm volatile("s_waitcnt vmcnt(0)" ::: "memory");
    }
    __builtin_amdgcn_s_barrier();
    asm volatile("" ::: "memory");
    const float* bufA = ldsA[ks & 1];
    const unsigned short* bufB = ldsB[ks & 1];
    bf16x8 af[4], bf[4];
    #pragma unroll
    for (int mi = 0; mi < 4; mi++) {
      const int arow = wr + mi * 16 + rr;
      const int e = arow & 7;
      const float4 f0 = *(const float4*)&bufA[(arow * 8 + ((2 * gk) ^ e)) * 4];
      const float4 f1 = *(const float4*)&bufA[(arow * 8 + ((2 * gk + 1) ^ e)) * 4];
      uint4 au;
      au.x = cvt_pk_bf16(f0.x, f0.y);
      au.y = cvt_pk_bf16(f0.z, f0.w);
      au.z = cvt_pk_bf16(f1.x, f1.y);
      au.w = cvt_pk_bf16(f1.z, f1.w);
      af[mi] = __builtin_bit_cast(bf16x8, au);
    }
    #pragma unroll
    for (int ni = 0; ni < 4; ni++)
      bf[ni] = __builtin_bit_cast(bf16x8,
          *(const uint4*)&bufB[((wc + ni * 16 + rr) * 4 + (gk ^ swz)) * 8]);
    #pragma unroll
    for (int mi = 0; mi < 4; mi++)
      #pragma unroll
      for (int ni = 0; ni < 4; ni++)
        acc[mi][ni] = __builtin_amdgcn_mfma_f32_16x16x32_bf16(af[mi], bf[ni], acc[mi][ni], 0, 0, 0);
    asm volatile("" ::: "memory");
    __builtin_amdgcn_s_barrier();
  }

  #pragma unroll
  for (int mi = 0; mi < 4; mi++) {
    const int rbase = wr + mi * 16 + (lane >> 4) * 4;
    #pragma unroll
    for (int ni = 0; ni < 4; ni++) {
      const int c_ = wc + ni * 16 + (lane & 15);
      const float bv = bias[col0 + c_];
      #pragma unroll
      for (int r = 0; r < 4; r++) {
        Out[(row0 + rbase + r) * (long)ldo + col0 + c_] = f2bf(acc[mi][ni][r] + bv);
      }
    }
  }
}

// ---------------- GEMM: 128x128, 2-buffer, counted vmcnt(4), bounds(256,4) -------
// (r11 best-measured config.)  OutF: fp32 secondary output, cols < 68 (fc3 path).
__global__ __launch_bounds__(256, 4) void gemm_glds(
    const unsigned short* __restrict__ A, int lda, int zAoff,
    const unsigned short* __restrict__ W, int zWoff,
    const float* __restrict__ bias, int zBoff,
    unsigned short* __restrict__ Out, int ldo, int zOoff, int lnN,
    float* __restrict__ OutF) {
  __shared__ unsigned short lds[2][8192];   // 32 KiB
  const int z = blockIdx.z;
  const unsigned short* Az = A + (long)z * zAoff;
  const unsigned short* Wz = W + (long)z * zWoff;
  const float* biasz = bias + z * zBoff;
  unsigned short* Outz = Out + (long)z * zOoff;

  const int nwg = gridDim.x;
  const int bid = blockIdx.x;
  const int wg = (bid & 7) * (nwg >> 3) + (bid >> 3);
  const int mtile = wg >> lnN;
  const int ntile = wg & ((1 << lnN) - 1);
  const long row0 = (long)mtile * 128;
  const int col0 = ntile * 128;

  const int tid = threadIdx.x;
  const int lane = tid & 63;
  const int wid = tid >> 6;
  const int wr = (wid >> 1) * 64;
  const int wc = (wid & 1) * 64;
  const int rr = lane & 15;
  const int gk = lane >> 4;
  const int swz = (rr >> 1) & 3;

  const int srow_l = (wid << 4) + (lane >> 2);
  const int sgl = lane & 3;

  f32x4 acc[4][4] = {};

  auto stage = [&](int buf, int k0) {
    #pragma unroll
    for (int j = 0; j < 4; j++) {
      const int slotbase = j * 256 + (wid << 6);
      unsigned short* ldst = &lds[buf][slotbase * 8];
      const int row = (j & 1) * 64 + srow_l;
      const int g = sgl ^ ((row >> 1) & 3);
      const unsigned short* src;
      if (j < 2) src = Az + (row0 + row) * (long)lda + k0 + g * 8;
      else       src = Wz + (long)(col0 + row) * 256 + k0 + g * 8;
      gload16(src, ldst);
    }
  };

  stage(0, 0);
  #pragma unroll
  for (int ks = 0; ks < 8; ks++) {
    if (ks < 7) {
      stage((ks + 1) & 1, (ks + 1) * 32);
      asm volatile("s_waitcnt vmcnt(4)" ::: "memory");
    } else {
      asm volatile("s_waitcnt vmcnt(0)" ::: "memory");
    }
    __builtin_amdgcn_s_barrier();
    asm volatile("" ::: "memory");
    const unsigned short* buf = lds[ks & 1];
    bf16x8 af[4], bf[4];
    #pragma unroll
    for (int mi = 0; mi < 4; mi++)
      af[mi] = __builtin_bit_cast(bf16x8,
          *(const uint4*)&buf[(wr + mi * 16 + rr) * 32 + ((gk ^ swz) * 8)]);
    #pragma unroll
    for (int ni = 0; ni < 4; ni++)
      bf[ni] = __builtin_bit_cast(bf16x8,
          *(const uint4*)&buf[4096 + (wc + ni * 16 + rr) * 32 + ((gk ^ swz) * 8)]);
    #pragma unroll
    for (int mi = 0; mi < 4; mi++)
      #pragma unroll
      for (int ni = 0; ni < 4; ni++)
        acc[mi][ni] = __builtin_amdgcn_mfma_f32_16x16x32_bf16(af[mi], bf[ni], acc[mi][ni], 0, 0, 0);
    asm volatile("" ::: "memory");
    __builtin_amdgcn_s_barrier();
  }

  #pragma unroll
  for (int mi = 0; mi < 4; mi++) {
    const int rbase = wr + mi * 16 + (lane >> 4) * 4;
    #pragma unroll
    for (int ni = 0; ni < 4; ni++) {
      const int c_ = wc + ni * 16 + (lane & 15);
      const float bv = biasz[col0 + c_];
      #pragma unroll
      for (int r = 0; r < 4; r++) {
        const float val = acc[mi][ni][r] + bv;
        Outz[(row0 + rbase + r) * (long)ldo + col0 + c_] = f2bf(val);
        if (OutF != nullptr && c_ < 68)
          OutF[(row0 + rbase + r) * 68L + c_] = val;
      }
    }
  }
}

// ---------------- depthwise 3x3 + bias + fast GELU, 4 pixels/thread ----------------
// CLS: lanes 0-31 (c-branch) don't store; instead compute fc3_c dot (256ch) -> cls_logit.
template <bool CLS>
__global__ __launch_bounds__(256) void dwconv_gelu4(
    const unsigned short* __restrict__ In,
    const float* __restrict__ Wt, const float* __restrict__ Bt,
    unsigned short* __restrict__ Out,
    const unsigned short* __restrict__ Wc3, const float* __restrict__ bc3,
    float* __restrict__ cls_logit) {
  const int t = blockIdx.x * 256 + threadIdx.x;  // 32768 quads * 64 groups
  const int g = t & 63;
  const int p = t >> 6;
  const int n = p >> 10;
  const int h = (p >> 4) & 63;
  const int w0 = (p & 15) << 2;
  const int cbase = g << 3;
  f32x2 acc[4][4];
  {
    float4 b0 = *(const float4*)(Bt + cbase);
    float4 b1 = *(const float4*)(Bt + cbase + 4);
    f32x2 bb[4];
    bb[0].x = b0.x; bb[0].y = b0.y; bb[1].x = b0.z; bb[1].y = b0.w;
    bb[2].x = b1.x; bb[2].y = b1.y; bb[3].x = b1.z; bb[3].y = b1.w;
    #pragma unroll
    for (int k = 0; k < 4; k++)
      #pragma unroll
      for (int i = 0; i < 4; i++) acc[k][i] = bb[i];
  }
  #pragma unroll
  for (int dy = -1; dy <= 1; dy++) {
    const int hh = h + dy;
    if (hh < 0 || hh > 63) continue;           // wave-uniform
    const float* wbase = Wt + ((dy + 1) * 3) * 512 + cbase;
    f32x2 wt[3][4];
    #pragma unroll
    for (int j = 0; j < 3; j++) {
      float4 a0 = *(const float4*)(wbase + j * 512);
      float4 a1 = *(const float4*)(wbase + j * 512 + 4);
      wt[j][0].x = a0.x; wt[j][0].y = a0.y; wt[j][1].x = a0.z; wt[j][1].y = a0.w;
      wt[j][2].x = a1.x; wt[j][2].y = a1.y; wt[j][3].x = a1.z; wt[j][3].y = a1.w;
    }
    const long rowtok = (long)(((n << 6) + hh) << 6);
    f32x2 f[6][4];
    #pragma unroll
    for (int d = 0; d < 6; d++) {
      const int col = w0 - 1 + d;
      uint4 v = {0u, 0u, 0u, 0u};
      if (col >= 0 && col < 64)                // only d=0/d=5 can fail; wave-uniform
        v = *(const uint4*)(In + (rowtok + col) * 512 + cbase);
      f[d][0] = unpack2(v.x); f[d][1] = unpack2(v.y);
      f[d][2] = unpack2(v.z); f[d][3] = unpack2(v.w);
    }
    #pragma unroll
    for (int k = 0; k < 4; k++)
      #pragma unroll
      for (int j = 0; j < 3; j++)
        #pragma unroll
        for (int i = 0; i < 4; i++)
          acc[k][i] += f[k + j][i] * wt[j][i];
  }
  f32x2 w3[4];
  if (CLS) {
    const int cc = cbase & 255;
    uint4 wv = *(const uint4*)(Wc3 + cc);
    w3[0] = unpack2(wv.x); w3[1] = unpack2(wv.y);
    w3[2] = unpack2(wv.z); w3[3] = unpack2(wv.w);
  }
  const long mbase = ((long)((n << 6) + h) << 6) + w0;
  float s[4];
  #pragma unroll
  for (int k = 0; k < 4; k++) {
    __align__(16) unsigned int ov[4];
    f32x2 ge[4];
    #pragma unroll
    for (int i = 0; i < 4; i++) {
      ge[i] = gelu2(acc[k][i]);
      ov[i] = cvt_pk_bf16(ge[i].x, ge[i].y);
    }
    if (!CLS || cbase >= 256)
      *(uint4*)(Out + (mbase + k) * 512 + cbase) = *(uint4*)ov;
    if (CLS) {
      f32x2 sp = ge[0] * w3[0] + ge[1] * w3[1] + ge[2] * w3[2] + ge[3] * w3[3];
      s[k] = sp.x + sp.y;
    }
  }
  if (CLS) {
    #pragma unroll
    for (int k = 0; k < 4; k++) {
      #pragma unroll
      for (int m = 16; m >= 1; m >>= 1) s[k] += __shfl_xor(s[k], m);
    }
    if (g == 0) {
      float b = bc3[0];
      float4 o;
      o.x = s[0] + b; o.y = s[1] + b; o.z = s[2] + b; o.w = s[3] + b;
      *(float4*)(cls_logit + mbase) = o;
    }
  }
}

// ---------------- post: softmax-17, boxes, top4, q-net, cls fuse ----------------
// out_reg is written by the fc3 GEMM; here only cls + boxes.
__global__ __launch_bounds__(256) void post_kernel(
    const unsigned short* __restrict__ RP,
    const float* __restrict__ cls_logit,
    const float* __restrict__ rc1_w, const float* __restrict__ rc1_b,
    const float* __restrict__ rc2_w, const float* __restrict__ rc2_b,
    float* __restrict__ out_cls, float* __restrict__ out_boxes) {
  int m = blockIdx.x * 256 + threadIdx.x;
  const unsigned short* rp = RP + (long)m * 128;
  __align__(16) unsigned short raw[72];
  #pragma unroll
  for (int q = 0; q < 9; q++)
    *(uint4*)(raw + q * 8) = *(const uint4*)(rp + q * 8);
  float stat[20];
  float4 boxes;
  #pragma unroll
  for (int s = 0; s < 4; s++) {
    float v[17];
    float mx = -1e30f;
    #pragma unroll
    for (int i = 0; i < 17; i++) {
      v[i] = bf2f(raw[s * 17 + i]);
      mx = fmaxf(mx, v[i]);
    }
    float sum = 0.f;
    #pragma unroll
    for (int i = 0; i < 17; i++) { v[i] = __expf(v[i] - mx); sum += v[i]; }
    float inv = 1.f / sum;
    float dist = 0.f;
    #pragma unroll
    for (int i = 0; i < 17; i++) { v[i] *= inv; dist += v[i] * (float)i; }
    ((float*)&boxes)[s] = dist * 0.0625f;
    float tk[4];
    #pragma unroll
    for (int t = 0; t < 4; t++) {
      float bm = v[0]; int bi = 0;
      #pragma unroll
      for (int i = 1; i < 17; i++) {
        if (v[i] > bm) { bm = v[i]; bi = i; }
      }
      tk[t] = bm;
      #pragma unroll
      for (int i = 0; i < 17; i++)
        if (i == bi) v[i] = -1.f;
    }
    stat[s * 5 + 0] = tk[0]; stat[s * 5 + 1] = tk[1];
    stat[s * 5 + 2] = tk[2]; stat[s * 5 + 3] = tk[3];
    stat[s * 5 + 4] = 0.25f * (tk[0] + tk[1] + tk[2] + tk[3]);
  }
  *(float4*)(out_boxes + (long)m * 4) = boxes;
  float z = 0.f;
  #pragma unroll
  for (int o = 0; o < 64; o++) {
    float q = rc1_b[o];
    #pragma unroll
    for (int c = 0; c < 20; c++) q += rc1_w[o * 20 + c] * stat[c];
    q = fmaxf(q, 0.f);
    z += q * rc2_w[o];
  }
  z += rc2_b[0];
  float q2 = 1.f / (1.f + __expf(-z));
  float cl = 1.f / (1.f + __expf(-cls_logit[m]));
  out_cls[m] = cl * q2;
}

extern "C" void kernel_launch(void* const* d_in, const int* in_sizes, int n_in,
                              void* d_out, int out_size, void* d_ws, size_t ws_size,
                              hipStream_t stream) {
  const float* x       = (const float*)d_in[0];
  const float* c_fc1_w = (const float*)d_in[1];
  const float* c_fc1_b = (const float*)d_in[2];
  const float* c_dw1_w = (const float*)d_in[3];
  const float* c_dw1_b = (const float*)d_in[4];
  const float* c_fc2_w = (const float*)d_in[5];
  const float* c_fc2_b = (const float*)d_in[6];
  const float* c_dw2_w = (const float*)d_in[7];
  const float* c_dw2_b = (const float*)d_in[8];
  const float* c_fc3_w = (const float*)d_in[9];
  const float* c_fc3_b = (const float*)d_in[10];
  const float* r_fc1_w = (const float*)d_in[11];
  const float* r_fc1_b = (const float*)d_in[12];
  const float* r_dw1_w = (const float*)d_in[13];
  const float* r_dw1_b = (const float*)d_in[14];
  const float* r_fc2_w = (const float*)d_in[15];
  const float* r_fc2_b = (const float*)d_in[16];
  const float* r_dw2_w = (const float*)d_in[17];
  const float* r_dw2_b = (const float*)d_in[18];
  const float* r_fc3_w = (const float*)d_in[19];
  const float* r_fc3_b = (const float*)d_in[20];
  const float* rc1_w   = (const float*)d_in[21];
  const float* rc1_b   = (const float*)d_in[22];
  const float* rc2_w   = (const float*)d_in[23];
  const float* rc2_b   = (const float*)d_in[24];

  char* ws = (char*)d_ws;
  unsigned short* Hbuf = (unsigned short*)ws;                       // 128 MiB
  unsigned short* Gbuf = (unsigned short*)(ws + 134217728L);        // 128 MiB
  unsigned short* RP   = (unsigned short*)(ws + 268435456L);        // 32 MiB
  float* cls_logit     = (float*)(ws + 301989888L);                 // 512 KiB
  char* wb             = ws + 302514176L;
  unsigned short* w1cat  = (unsigned short*)wb;          // 131072 bf16 (c_fc1|r_fc1)
  unsigned short* w2cat  = w1cat + 131072;               // 131072 bf16 (c_fc2|r_fc2)
  unsigned short* c3wb   = w2cat + 131072;               // 256
  unsigned short* wr3pad = c3wb + 256;                   // 32768
  float* br3pad = (float*)(wr3pad + 32768);              // 128
  float* b1cat  = br3pad + 128;                          // 512
  float* b2cat  = b1cat + 512;                           // 512
  float* wd1    = b2cat + 512;                           // 4608
  float* bd1    = wd1 + 4608;                            // 512
  float* wd2    = bd1 + 512;                             // 4608
  float* bd2    = wd2 + 4608;                            // 512

  float* out_cls   = (float*)d_out;
  float* out_boxes = out_cls + 131072;
  float* out_reg   = out_boxes + 524288;

  prep_all<<<1024, 256, 0, stream>>>(
      c_fc1_w, r_fc1_w, c_fc2_w, r_fc2_w, c_fc3_w, r_fc3_w, r_fc3_b,
      c_fc1_b, r_fc1_b, c_fc2_b, r_fc2_b,
      c_dw1_w, c_dw1_b, r_dw1_w, r_dw1_b,
      c_dw2_w, c_dw2_b, r_dw2_w, r_dw2_b,
      w1cat, w2cat, c3wb, wr3pad, br3pad, b1cat, b2cat,
      wd1, bd1, wd2, bd2);

  // fc1: A = x fp32 via global_load_lds (dbuf per K-step), N=512 (nN=4)
  gemm_xa<<<dim3(4096, 1, 1), 256, 0, stream>>>(
      x, w1cat, b1cat, Hbuf, 512, 2);
  // dwconv1 + gelu (stores both halves)
  dwconv_gelu4<false><<<8192, 256, 0, stream>>>(Hbuf, wd1, bd1, Gbuf,
                                                nullptr, nullptr, nullptr);
  // fc2: branches via z (nN=2 per branch)
  gemm_glds<<<dim3(2048, 1, 2), 256, 0, stream>>>(
      Gbuf, 512, 256, w2cat, 65536, b2cat, 256, Hbuf, 512, 256, 1, nullptr);
  // dwconv2 + gelu + fused cls dot (stores only r-half)
  dwconv_gelu4<true><<<8192, 256, 0, stream>>>(Hbuf, wd2, bd2, Gbuf,
                                               c3wb, c_fc3_b, cls_logit);
  // fc3 (r-half): bf16 RP for post + fp32 out_reg directly
  gemm_glds<<<dim3(1024, 1, 1), 256, 0, stream>>>(
      Gbuf + 256, 512, 0, wr3pad, 0, br3pad, 0, RP, 128, 0, 0, out_reg);
  // post (cls + boxes only)
  post_kernel<<<512, 256, 0, stream>>>(RP, cls_logit, rc1_w, rc1_b, rc2_w, rc2_b,
                                       out_cls, out_boxes);
}

// Round 20
// 345.403 us; speedup vs baseline: 1.1379x; 1.0463x over previous
//
#include <hip/hip_runtime.h>
#include <hip/hip_bf16.h>

typedef __bf16 bf16x8 __attribute__((ext_vector_type(8)));
typedef float f32x4 __attribute__((ext_vector_type(4)));
typedef float f32x2 __attribute__((ext_vector_type(2)));

__device__ __forceinline__ float bf2f(unsigned short b) {
  unsigned int u = ((unsigned int)b) << 16;
  return __builtin_bit_cast(float, u);
}
__device__ __forceinline__ unsigned short f2bf(float f) {
  unsigned int u = __builtin_bit_cast(unsigned int, f);
  unsigned int r = u + 0x7fffu + ((u >> 16) & 1u);
  return (unsigned short)(r >> 16);
}
__device__ __forceinline__ f32x2 unpack2(unsigned int u) {
  f32x2 r;
  r.x = __builtin_bit_cast(float, u << 16);
  r.y = __builtin_bit_cast(float, u & 0xffff0000u);
  return r;
}

__device__ __forceinline__ void gload16(const void* g, void* l) {
  typedef __attribute__((address_space(1))) const void* gp_t;
  typedef __attribute__((address_space(3))) void* lp_t;
  __builtin_amdgcn_global_load_lds((gp_t)g, (lp_t)l, 16, 0, 0);
}

// fast GELU: x * sigmoid(1.5958(x + 0.044715 x^3)), |err vs exact erf| <= ~5e-4.
__device__ __forceinline__ f32x2 gelu2(f32x2 x) {
  f32x2 m = x * x;
  f32x2 t = m * (-0.10295273f) + (-2.3021967f);
  f32x2 u = x * t;
  f32x2 e;
  e.x = __builtin_amdgcn_exp2f(u.x);
  e.y = __builtin_amdgcn_exp2f(u.y);
  f32x2 d = e + 1.0f;
  f32x2 r;
  r.x = __builtin_amdgcn_rcpf(d.x);
  r.y = __builtin_amdgcn_rcpf(d.y);
  return x * r;
}
__device__ __forceinline__ unsigned int cvt_pk_bf16(float lo, float hi) {
  unsigned int r;
  asm("v_cvt_pk_bf16_f32 %0, %1, %2" : "=v"(r) : "v"(lo), "v"(hi));
  return r;
}

// ---------------- x fp32 -> bf16 ----------------
__global__ __launch_bounds__(256) void cvt_x(const float* __restrict__ in,
                                             unsigned short* __restrict__ out) {
  long i = ((long)blockIdx.x * 256 + threadIdx.x) * 8;
  float4 a = *(const float4*)(in + i);
  float4 b = *(const float4*)(in + i + 4);
  __align__(16) unsigned short o[8];
  o[0] = f2bf(a.x); o[1] = f2bf(a.y); o[2] = f2bf(a.z); o[3] = f2bf(a.w);
  o[4] = f2bf(b.x); o[5] = f2bf(b.y); o[6] = f2bf(b.z); o[7] = f2bf(b.w);
  *(uint4*)(out + i) = *(uint4*)o;
}

// ---------------- fused weight prep (one dispatch) ----------------
__global__ __launch_bounds__(256) void prep_all(
    const float* __restrict__ c1w, const float* __restrict__ r1w,
    const float* __restrict__ c2w, const float* __restrict__ r2w,
    const float* __restrict__ c3w, const float* __restrict__ r3w, const float* __restrict__ r3b,
    const float* __restrict__ c1b, const float* __restrict__ r1b,
    const float* __restrict__ c2b, const float* __restrict__ r2b,
    const float* __restrict__ d1wc, const float* __restrict__ d1bc,
    const float* __restrict__ d1wr, const float* __restrict__ d1br,
    const float* __restrict__ d2wc, const float* __restrict__ d2bc,
    const float* __restrict__ d2wr, const float* __restrict__ d2br,
    unsigned short* __restrict__ w1cat, unsigned short* __restrict__ w2cat,
    unsigned short* __restrict__ c3wb, unsigned short* __restrict__ wr3pad,
    float* __restrict__ br3pad, float* __restrict__ b1cat, float* __restrict__ b2cat,
    float* __restrict__ wd1, float* __restrict__ bd1,
    float* __restrict__ wd2, float* __restrict__ bd2) {
  int i = blockIdx.x * 256 + threadIdx.x;  // 262144
  {
    int which = i >> 16, j = i & 65535;
    float v = (which == 0) ? c1w[j] : (which == 1) ? r1w[j] : (which == 2) ? c2w[j] : r2w[j];
    unsigned short* dst = (which < 2) ? (w1cat + which * 65536) : (w2cat + (which - 2) * 65536);
    dst[j] = f2bf(v);
  }
  if (i < 32768) {
    int r = i >> 8, c = i & 255;
    wr3pad[i] = (r < 68) ? f2bf(r3w[r * 256 + c]) : (unsigned short)0;
    if (i < 128) br3pad[i] = (i < 68) ? r3b[i] : 0.f;
  }
  if (i < 256) c3wb[i] = f2bf(c3w[i]);
  if (i < 4608) {
    int tap = i >> 9, ch = i & 511, cc = ch & 255;
    wd1[i] = (ch < 256) ? d1wc[cc * 9 + tap] : d1wr[cc * 9 + tap];
    wd2[i] = (ch < 256) ? d2wc[cc * 9 + tap] : d2wr[cc * 9 + tap];
  }
  if (i < 512) {
    bd1[i] = (i < 256) ? d1bc[i] : d1br[i & 255];
    bd2[i] = (i < 256) ? d2bc[i] : d2br[i & 255];
    b1cat[i] = (i < 256) ? c1b[i] : r1b[i & 255];
    b2cat[i] = (i < 256) ? c2b[i] : r2b[i & 255];
  }
}

// ---------------- GEMM: 128x128, 2-buffer, counted vmcnt(4), bounds(256,4) -------
// (r11 best-measured config.)  OutF: fp32 secondary output, cols < 68 (fc3 path).
__global__ __launch_bounds__(256, 4) void gemm_glds(
    const unsigned short* __restrict__ A, int lda, int zAoff,
    const unsigned short* __restrict__ W, int zWoff,
    const float* __restrict__ bias, int zBoff,
    unsigned short* __restrict__ Out, int ldo, int zOoff, int lnN,
    float* __restrict__ OutF) {
  __shared__ unsigned short lds[2][8192];   // 32 KiB
  const int z = blockIdx.z;
  const unsigned short* Az = A + (long)z * zAoff;
  const unsigned short* Wz = W + (long)z * zWoff;
  const float* biasz = bias + z * zBoff;
  unsigned short* Outz = Out + (long)z * zOoff;

  const int nwg = gridDim.x;
  const int bid = blockIdx.x;
  const int wg = (bid & 7) * (nwg >> 3) + (bid >> 3);
  const int mtile = wg >> lnN;
  const int ntile = wg & ((1 << lnN) - 1);
  const long row0 = (long)mtile * 128;
  const int col0 = ntile * 128;

  const int tid = threadIdx.x;
  const int lane = tid & 63;
  const int wid = tid >> 6;
  const int wr = (wid >> 1) * 64;
  const int wc = (wid & 1) * 64;
  const int rr = lane & 15;
  const int gk = lane >> 4;
  const int swz = (rr >> 1) & 3;

  const int srow_l = (wid << 4) + (lane >> 2);
  const int sgl = lane & 3;

  f32x4 acc[4][4] = {};

  auto stage = [&](int buf, int k0) {
    #pragma unroll
    for (int j = 0; j < 4; j++) {
      const int slotbase = j * 256 + (wid << 6);
      unsigned short* ldst = &lds[buf][slotbase * 8];
      const int row = (j & 1) * 64 + srow_l;
      const int g = sgl ^ ((row >> 1) & 3);
      const unsigned short* src;
      if (j < 2) src = Az + (row0 + row) * (long)lda + k0 + g * 8;
      else       src = Wz + (long)(col0 + row) * 256 + k0 + g * 8;
      gload16(src, ldst);
    }
  };

  stage(0, 0);
  #pragma unroll
  for (int ks = 0; ks < 8; ks++) {
    if (ks < 7) {
      stage((ks + 1) & 1, (ks + 1) * 32);
      asm volatile("s_waitcnt vmcnt(4)" ::: "memory");
    } else {
      asm volatile("s_waitcnt vmcnt(0)" ::: "memory");
    }
    __builtin_amdgcn_s_barrier();
    asm volatile("" ::: "memory");
    const unsigned short* buf = lds[ks & 1];
    bf16x8 af[4], bf[4];
    #pragma unroll
    for (int mi = 0; mi < 4; mi++)
      af[mi] = __builtin_bit_cast(bf16x8,
          *(const uint4*)&buf[(wr + mi * 16 + rr) * 32 + ((gk ^ swz) * 8)]);
    #pragma unroll
    for (int ni = 0; ni < 4; ni++)
      bf[ni] = __builtin_bit_cast(bf16x8,
          *(const uint4*)&buf[4096 + (wc + ni * 16 + rr) * 32 + ((gk ^ swz) * 8)]);
    #pragma unroll
    for (int mi = 0; mi < 4; mi++)
      #pragma unroll
      for (int ni = 0; ni < 4; ni++)
        acc[mi][ni] = __builtin_amdgcn_mfma_f32_16x16x32_bf16(af[mi], bf[ni], acc[mi][ni], 0, 0, 0);
    asm volatile("" ::: "memory");
    __builtin_amdgcn_s_barrier();
  }

  #pragma unroll
  for (int mi = 0; mi < 4; mi++) {
    const int rbase = wr + mi * 16 + (lane >> 4) * 4;
    #pragma unroll
    for (int ni = 0; ni < 4; ni++) {
      const int c_ = wc + ni * 16 + (lane & 15);
      const float bv = biasz[col0 + c_];
      #pragma unroll
      for (int r = 0; r < 4; r++) {
        const float val = acc[mi][ni][r] + bv;
        Outz[(row0 + rbase + r) * (long)ldo + col0 + c_] = f2bf(val);
        if (OutF != nullptr && c_ < 68)
          OutF[(row0 + rbase + r) * 68L + c_] = val;
      }
    }
  }
}

// ---------------- depthwise 3x3 + bias + fast GELU, 4 pixels/thread ----------------
// CLS: lanes 0-31 (c-branch) don't store; instead compute fc3_c dot (256ch) -> cls_logit.
template <bool CLS>
__global__ __launch_bounds__(256) void dwconv_gelu4(
    const unsigned short* __restrict__ In,
    const float* __restrict__ Wt, const float* __restrict__ Bt,
    unsigned short* __restrict__ Out,
    const unsigned short* __restrict__ Wc3, const float* __restrict__ bc3,
    float* __restrict__ cls_logit) {
  const int t = blockIdx.x * 256 + threadIdx.x;  // 32768 quads * 64 groups
  const int g = t & 63;
  const int p = t >> 6;
  const int n = p >> 10;
  const int h = (p >> 4) & 63;
  const int w0 = (p & 15) << 2;
  const int cbase = g << 3;
  f32x2 acc[4][4];
  {
    float4 b0 = *(const float4*)(Bt + cbase);
    float4 b1 = *(const float4*)(Bt + cbase + 4);
    f32x2 bb[4];
    bb[0].x = b0.x; bb[0].y = b0.y; bb[1].x = b0.z; bb[1].y = b0.w;
    bb[2].x = b1.x; bb[2].y = b1.y; bb[3].x = b1.z; bb[3].y = b1.w;
    #pragma unroll
    for (int k = 0; k < 4; k++)
      #pragma unroll
      for (int i = 0; i < 4; i++) acc[k][i] = bb[i];
  }
  #pragma unroll
  for (int dy = -1; dy <= 1; dy++) {
    const int hh = h + dy;
    if (hh < 0 || hh > 63) continue;           // wave-uniform
    const float* wbase = Wt + ((dy + 1) * 3) * 512 + cbase;
    f32x2 wt[3][4];
    #pragma unroll
    for (int j = 0; j < 3; j++) {
      float4 a0 = *(const float4*)(wbase + j * 512);
      float4 a1 = *(const float4*)(wbase + j * 512 + 4);
      wt[j][0].x = a0.x; wt[j][0].y = a0.y; wt[j][1].x = a0.z; wt[j][1].y = a0.w;
      wt[j][2].x = a1.x; wt[j][2].y = a1.y; wt[j][3].x = a1.z; wt[j][3].y = a1.w;
    }
    const long rowtok = (long)(((n << 6) + hh) << 6);
    f32x2 f[6][4];
    #pragma unroll
    for (int d = 0; d < 6; d++) {
      const int col = w0 - 1 + d;
      uint4 v = {0u, 0u, 0u, 0u};
      if (col >= 0 && col < 64)                // only d=0/d=5 can fail; wave-uniform
        v = *(const uint4*)(In + (rowtok + col) * 512 + cbase);
      f[d][0] = unpack2(v.x); f[d][1] = unpack2(v.y);
      f[d][2] = unpack2(v.z); f[d][3] = unpack2(v.w);
    }
    #pragma unroll
    for (int k = 0; k < 4; k++)
      #pragma unroll
      for (int j = 0; j < 3; j++)
        #pragma unroll
        for (int i = 0; i < 4; i++)
          acc[k][i] += f[k + j][i] * wt[j][i];
  }
  f32x2 w3[4];
  if (CLS) {
    const int cc = cbase & 255;
    uint4 wv = *(const uint4*)(Wc3 + cc);
    w3[0] = unpack2(wv.x); w3[1] = unpack2(wv.y);
    w3[2] = unpack2(wv.z); w3[3] = unpack2(wv.w);
  }
  const long mbase = ((long)((n << 6) + h) << 6) + w0;
  float s[4];
  #pragma unroll
  for (int k = 0; k < 4; k++) {
    __align__(16) unsigned int ov[4];
    f32x2 ge[4];
    #pragma unroll
    for (int i = 0; i < 4; i++) {
      ge[i] = gelu2(acc[k][i]);
      ov[i] = cvt_pk_bf16(ge[i].x, ge[i].y);
    }
    if (!CLS || cbase >= 256)
      *(uint4*)(Out + (mbase + k) * 512 + cbase) = *(uint4*)ov;
    if (CLS) {
      f32x2 sp = ge[0] * w3[0] + ge[1] * w3[1] + ge[2] * w3[2] + ge[3] * w3[3];
      s[k] = sp.x + sp.y;
    }
  }
  if (CLS) {
    #pragma unroll
    for (int k = 0; k < 4; k++) {
      #pragma unroll
      for (int m = 16; m >= 1; m >>= 1) s[k] += __shfl_xor(s[k], m);
    }
    if (g == 0) {
      float b = bc3[0];
      float4 o;
      o.x = s[0] + b; o.y = s[1] + b; o.z = s[2] + b; o.w = s[3] + b;
      *(float4*)(cls_logit + mbase) = o;
    }
  }
}

// ---------------- post: softmax-17, boxes, top4, q-net, cls fuse ----------------
// out_reg is written by the fc3 GEMM; here only cls + boxes.
__global__ __launch_bounds__(256) void post_kernel(
    const unsigned short* __restrict__ RP,
    const float* __restrict__ cls_logit,
    const float* __restrict__ rc1_w, const float* __restrict__ rc1_b,
    const float* __restrict__ rc2_w, const float* __restrict__ rc2_b,
    float* __restrict__ out_cls, float* __restrict__ out_boxes) {
  int m = blockIdx.x * 256 + threadIdx.x;
  const unsigned short* rp = RP + (long)m * 128;
  __align__(16) unsigned short raw[72];
  #pragma unroll
  for (int q = 0; q < 9; q++)
    *(uint4*)(raw + q * 8) = *(const uint4*)(rp + q * 8);
  float stat[20];
  float4 boxes;
  #pragma unroll
  for (int s = 0; s < 4; s++) {
    float v[17];
    float mx = -1e30f;
    #pragma unroll
    for (int i = 0; i < 17; i++) {
      v[i] = bf2f(raw[s * 17 + i]);
      mx = fmaxf(mx, v[i]);
    }
    float sum = 0.f;
    #pragma unroll
    for (int i = 0; i < 17; i++) { v[i] = __expf(v[i] - mx); sum += v[i]; }
    float inv = 1.f / sum;
    float dist = 0.f;
    #pragma unroll
    for (int i = 0; i < 17; i++) { v[i] *= inv; dist += v[i] * (float)i; }
    ((float*)&boxes)[s] = dist * 0.0625f;
    float tk[4];
    #pragma unroll
    for (int t = 0; t < 4; t++) {
      float bm = v[0]; int bi = 0;
      #pragma unroll
      for (int i = 1; i < 17; i++) {
        if (v[i] > bm) { bm = v[i]; bi = i; }
      }
      tk[t] = bm;
      #pragma unroll
      for (int i = 0; i < 17; i++)
        if (i == bi) v[i] = -1.f;
    }
    stat[s * 5 + 0] = tk[0]; stat[s * 5 + 1] = tk[1];
    stat[s * 5 + 2] = tk[2]; stat[s * 5 + 3] = tk[3];
    stat[s * 5 + 4] = 0.25f * (tk[0] + tk[1] + tk[2] + tk[3]);
  }
  *(float4*)(out_boxes + (long)m * 4) = boxes;
  float z = 0.f;
  #pragma unroll
  for (int o = 0; o < 64; o++) {
    float q = rc1_b[o];
    #pragma unroll
    for (int c = 0; c < 20; c++) q += rc1_w[o * 20 + c] * stat[c];
    q = fmaxf(q, 0.f);
    z += q * rc2_w[o];
  }
  z += rc2_b[0];
  float q2 = 1.f / (1.f + __expf(-z));
  float cl = 1.f / (1.f + __expf(-cls_logit[m]));
  out_cls[m] = cl * q2;
}

extern "C" void kernel_launch(void* const* d_in, const int* in_sizes, int n_in,
                              void* d_out, int out_size, void* d_ws, size_t ws_size,
                              hipStream_t stream) {
  const float* x       = (const float*)d_in[0];
  const float* c_fc1_w = (const float*)d_in[1];
  const float* c_fc1_b = (const float*)d_in[2];
  const float* c_dw1_w = (const float*)d_in[3];
  const float* c_dw1_b = (const float*)d_in[4];
  const float* c_fc2_w = (const float*)d_in[5];
  const float* c_fc2_b = (const float*)d_in[6];
  const float* c_dw2_w = (const float*)d_in[7];
  const float* c_dw2_b = (const float*)d_in[8];
  const float* c_fc3_w = (const float*)d_in[9];
  const float* c_fc3_b = (const float*)d_in[10];
  const float* r_fc1_w = (const float*)d_in[11];
  const float* r_fc1_b = (const float*)d_in[12];
  const float* r_dw1_w = (const float*)d_in[13];
  const float* r_dw1_b = (const float*)d_in[14];
  const float* r_fc2_w = (const float*)d_in[15];
  const float* r_fc2_b = (const float*)d_in[16];
  const float* r_dw2_w = (const float*)d_in[17];
  const float* r_dw2_b = (const float*)d_in[18];
  const float* r_fc3_w = (const float*)d_in[19];
  const float* r_fc3_b = (const float*)d_in[20];
  const float* rc1_w   = (const float*)d_in[21];
  const float* rc1_b   = (const float*)d_in[22];
  const float* rc2_w   = (const float*)d_in[23];
  const float* rc2_b   = (const float*)d_in[24];

  char* ws = (char*)d_ws;
  unsigned short* Hbuf = (unsigned short*)ws;                       // 128 MiB
  unsigned short* Gbuf = (unsigned short*)(ws + 134217728L);        // 128 MiB
  unsigned short* xb   = Gbuf;                                      // 64 MiB alias (dead after fc1)
  unsigned short* RP   = (unsigned short*)(ws + 268435456L);        // 32 MiB
  float* cls_logit     = (float*)(ws + 301989888L);                 // 512 KiB
  char* wb             = ws + 302514176L;
  unsigned short* w1cat  = (unsigned short*)wb;          // 131072 bf16 (c_fc1|r_fc1)
  unsigned short* w2cat  = w1cat + 131072;               // 131072 bf16 (c_fc2|r_fc2)
  unsigned short* c3wb   = w2cat + 131072;               // 256
  unsigned short* wr3pad = c3wb + 256;                   // 32768
  float* br3pad = (float*)(wr3pad + 32768);              // 128
  float* b1cat  = br3pad + 128;                          // 512
  float* b2cat  = b1cat + 512;                           // 512
  float* wd1    = b2cat + 512;                           // 4608
  float* bd1    = wd1 + 4608;                            // 512
  float* wd2    = bd1 + 512;                             // 4608
  float* bd2    = wd2 + 4608;                            // 512

  float* out_cls   = (float*)d_out;
  float* out_boxes = out_cls + 131072;
  float* out_reg   = out_boxes + 524288;

  prep_all<<<1024, 256, 0, stream>>>(
      c_fc1_w, r_fc1_w, c_fc2_w, r_fc2_w, c_fc3_w, r_fc3_w, r_fc3_b,
      c_fc1_b, r_fc1_b, c_fc2_b, r_fc2_b,
      c_dw1_w, c_dw1_b, r_dw1_w, r_dw1_b,
      c_dw2_w, c_dw2_b, r_dw2_w, r_dw2_b,
      w1cat, w2cat, c3wb, wr3pad, br3pad, b1cat, b2cat,
      wd1, bd1, wd2, bd2);
  cvt_x<<<16384, 256, 0, stream>>>(x, xb);

  // fc1: A = xb (bf16, lda 256), N=512 (nN=4)
  gemm_glds<<<dim3(4096, 1, 1), 256, 0, stream>>>(
      xb, 256, 0, w1cat, 0, b1cat, 0, Hbuf, 512, 0, 2, nullptr);
  // dwconv1 + gelu (stores both halves)
  dwconv_gelu4<false><<<8192, 256, 0, stream>>>(Hbuf, wd1, bd1, Gbuf,
                                                nullptr, nullptr, nullptr);
  // fc2: branches via z (nN=2 per branch)
  gemm_glds<<<dim3(2048, 1, 2), 256, 0, stream>>>(
      Gbuf, 512, 256, w2cat, 65536, b2cat, 256, Hbuf, 512, 256, 1, nullptr);
  // dwconv2 + gelu + fused cls dot (stores only r-half)
  dwconv_gelu4<true><<<8192, 256, 0, stream>>>(Hbuf, wd2, bd2, Gbuf,
                                               c3wb, c_fc3_b, cls_logit);
  // fc3 (r-half): bf16 RP for post + fp32 out_reg directly
  gemm_glds<<<dim3(1024, 1, 1), 256, 0, stream>>>(
      Gbuf + 256, 512, 0, wr3pad, 0, br3pad, 0, RP, 128, 0, 0, out_reg);
  // post (cls + boxes only)
  post_kernel<<<512, 256, 0, stream>>>(RP, cls_logit, rc1_w, rc1_b, rc2_w, rc2_b,
                                       out_cls, out_boxes);
}

// Round 21
// 330.469 us; speedup vs baseline: 1.1893x; 1.0452x over previous
//
#include <hip/hip_runtime.h>
#include <hip/hip_bf16.h>

typedef __bf16 bf16x8 __attribute__((ext_vector_type(8)));
typedef float f32x4 __attribute__((ext_vector_type(4)));
typedef float f32x2 __attribute__((ext_vector_type(2)));

__device__ __forceinline__ float bf2f(unsigned short b) {
  unsigned int u = ((unsigned int)b) << 16;
  return __builtin_bit_cast(float, u);
}
__device__ __forceinline__ unsigned short f2bf(float f) {
  unsigned int u = __builtin_bit_cast(unsigned int, f);
  unsigned int r = u + 0x7fffu + ((u >> 16) & 1u);
  return (unsigned short)(r >> 16);
}
__device__ __forceinline__ f32x2 unpack2(unsigned int u) {
  f32x2 r;
  r.x = __builtin_bit_cast(float, u << 16);
  r.y = __builtin_bit_cast(float, u & 0xffff0000u);
  return r;
}

__device__ __forceinline__ void gload16(const void* g, void* l) {
  typedef __attribute__((address_space(1))) const void* gp_t;
  typedef __attribute__((address_space(3))) void* lp_t;
  __builtin_amdgcn_global_load_lds((gp_t)g, (lp_t)l, 16, 0, 0);
}

// fast GELU: x * sigmoid(1.5958(x + 0.044715 x^3)), |err vs exact erf| <= ~5e-4.
__device__ __forceinline__ f32x2 gelu2(f32x2 x) {
  f32x2 m = x * x;
  f32x2 t = m * (-0.10295273f) + (-2.3021967f);
  f32x2 u = x * t;
  f32x2 e;
  e.x = __builtin_amdgcn_exp2f(u.x);
  e.y = __builtin_amdgcn_exp2f(u.y);
  f32x2 d = e + 1.0f;
  f32x2 r;
  r.x = __builtin_amdgcn_rcpf(d.x);
  r.y = __builtin_amdgcn_rcpf(d.y);
  return x * r;
}
__device__ __forceinline__ unsigned int cvt_pk_bf16(float lo, float hi) {
  unsigned int r;
  asm("v_cvt_pk_bf16_f32 %0, %1, %2" : "=v"(r) : "v"(lo), "v"(hi));
  return r;
}

// ---------------- fused prep: x fp32->bf16 (all blocks) + weight prep (low blocks) ----
__global__ __launch_bounds__(256) void prep_all(
    const float* __restrict__ x, unsigned short* __restrict__ xb,
    const float* __restrict__ c1w, const float* __restrict__ r1w,
    const float* __restrict__ c2w, const float* __restrict__ r2w,
    const float* __restrict__ c3w, const float* __restrict__ r3w, const float* __restrict__ r3b,
    const float* __restrict__ c1b, const float* __restrict__ r1b,
    const float* __restrict__ c2b, const float* __restrict__ r2b,
    const float* __restrict__ d1wc, const float* __restrict__ d1bc,
    const float* __restrict__ d1wr, const float* __restrict__ d1br,
    const float* __restrict__ d2wc, const float* __restrict__ d2bc,
    const float* __restrict__ d2wr, const float* __restrict__ d2br,
    unsigned short* __restrict__ w1cat, unsigned short* __restrict__ w2cat,
    unsigned short* __restrict__ c3wb, unsigned short* __restrict__ wr3pad,
    float* __restrict__ br3pad, float* __restrict__ b1cat, float* __restrict__ b2cat,
    float* __restrict__ wd1, float* __restrict__ bd1,
    float* __restrict__ wd2, float* __restrict__ bd2) {
  int i = blockIdx.x * 256 + threadIdx.x;  // 0 .. 4194303
  {
    long e = (long)i * 8;
    float4 a = *(const float4*)(x + e);
    float4 b = *(const float4*)(x + e + 4);
    __align__(16) unsigned short o[8];
    o[0] = f2bf(a.x); o[1] = f2bf(a.y); o[2] = f2bf(a.z); o[3] = f2bf(a.w);
    o[4] = f2bf(b.x); o[5] = f2bf(b.y); o[6] = f2bf(b.z); o[7] = f2bf(b.w);
    *(uint4*)(xb + e) = *(uint4*)o;
  }
  if (i < 262144) {
    int which = i >> 16, j = i & 65535;
    float v = (which == 0) ? c1w[j] : (which == 1) ? r1w[j] : (which == 2) ? c2w[j] : r2w[j];
    unsigned short* dst = (which < 2) ? (w1cat + which * 65536) : (w2cat + (which - 2) * 65536);
    dst[j] = f2bf(v);
  }
  if (i < 32768) {
    int r = i >> 8, c = i & 255;
    wr3pad[i] = (r < 68) ? f2bf(r3w[r * 256 + c]) : (unsigned short)0;
    if (i < 128) br3pad[i] = (i < 68) ? r3b[i] : 0.f;
  }
  if (i < 256) c3wb[i] = f2bf(c3w[i]);
  if (i < 4608) {
    int tap = i >> 9, ch = i & 511, cc = ch & 255;
    wd1[i] = (ch < 256) ? d1wc[cc * 9 + tap] : d1wr[cc * 9 + tap];
    wd2[i] = (ch < 256) ? d2wc[cc * 9 + tap] : d2wr[cc * 9 + tap];
  }
  if (i < 512) {
    bd1[i] = (i < 256) ? d1bc[i] : d1br[i & 255];
    bd2[i] = (i < 256) ? d2bc[i] : d2br[i & 255];
    b1cat[i] = (i < 256) ? c1b[i] : r1b[i & 255];
    b2cat[i] = (i < 256) ? c2b[i] : r2b[i & 255];
  }
}

// ---------------- GEMM: 128x128, 2-buffer, counted vmcnt(4), bounds(256,4) -------
// BF16OUT: write bf16 Out (fc1/fc2).  !BF16OUT: write only OutF fp32, cols<68 (fc3).
template <bool BF16OUT>
__global__ __launch_bounds__(256, 4) void gemm_glds(
    const unsigned short* __restrict__ A, int lda, int zAoff,
    const unsigned short* __restrict__ W, int zWoff,
    const float* __restrict__ bias, int zBoff,
    unsigned short* __restrict__ Out, int ldo, int zOoff, int lnN,
    float* __restrict__ OutF) {
  __shared__ unsigned short lds[2][8192];   // 32 KiB
  const int z = blockIdx.z;
  const unsigned short* Az = A + (long)z * zAoff;
  const unsigned short* Wz = W + (long)z * zWoff;
  const float* biasz = bias + z * zBoff;
  unsigned short* Outz = Out + (long)z * zOoff;

  const int nwg = gridDim.x;
  const int bid = blockIdx.x;
  const int wg = (bid & 7) * (nwg >> 3) + (bid >> 3);
  const int mtile = wg >> lnN;
  const int ntile = wg & ((1 << lnN) - 1);
  const long row0 = (long)mtile * 128;
  const int col0 = ntile * 128;

  const int tid = threadIdx.x;
  const int lane = tid & 63;
  const int wid = tid >> 6;
  const int wr = (wid >> 1) * 64;
  const int wc = (wid & 1) * 64;
  const int rr = lane & 15;
  const int gk = lane >> 4;
  const int swz = (rr >> 1) & 3;

  const int srow_l = (wid << 4) + (lane >> 2);
  const int sgl = lane & 3;

  f32x4 acc[4][4] = {};

  auto stage = [&](int buf, int k0) {
    #pragma unroll
    for (int j = 0; j < 4; j++) {
      const int slotbase = j * 256 + (wid << 6);
      unsigned short* ldst = &lds[buf][slotbase * 8];
      const int row = (j & 1) * 64 + srow_l;
      const int g = sgl ^ ((row >> 1) & 3);
      const unsigned short* src;
      if (j < 2) src = Az + (row0 + row) * (long)lda + k0 + g * 8;
      else       src = Wz + (long)(col0 + row) * 256 + k0 + g * 8;
      gload16(src, ldst);
    }
  };

  stage(0, 0);
  #pragma unroll
  for (int ks = 0; ks < 8; ks++) {
    if (ks < 7) {
      stage((ks + 1) & 1, (ks + 1) * 32);
      asm volatile("s_waitcnt vmcnt(4)" ::: "memory");
    } else {
      asm volatile("s_waitcnt vmcnt(0)" ::: "memory");
    }
    __builtin_amdgcn_s_barrier();
    asm volatile("" ::: "memory");
    const unsigned short* buf = lds[ks & 1];
    bf16x8 af[4], bf[4];
    #pragma unroll
    for (int mi = 0; mi < 4; mi++)
      af[mi] = __builtin_bit_cast(bf16x8,
          *(const uint4*)&buf[(wr + mi * 16 + rr) * 32 + ((gk ^ swz) * 8)]);
    #pragma unroll
    for (int ni = 0; ni < 4; ni++)
      bf[ni] = __builtin_bit_cast(bf16x8,
          *(const uint4*)&buf[4096 + (wc + ni * 16 + rr) * 32 + ((gk ^ swz) * 8)]);
    #pragma unroll
    for (int mi = 0; mi < 4; mi++)
      #pragma unroll
      for (int ni = 0; ni < 4; ni++)
        acc[mi][ni] = __builtin_amdgcn_mfma_f32_16x16x32_bf16(af[mi], bf[ni], acc[mi][ni], 0, 0, 0);
    asm volatile("" ::: "memory");
    __builtin_amdgcn_s_barrier();
  }

  #pragma unroll
  for (int mi = 0; mi < 4; mi++) {
    const int rbase = wr + mi * 16 + (lane >> 4) * 4;
    #pragma unroll
    for (int ni = 0; ni < 4; ni++) {
      const int c_ = wc + ni * 16 + (lane & 15);
      const float bv = biasz[col0 + c_];
      #pragma unroll
      for (int r = 0; r < 4; r++) {
        const float val = acc[mi][ni][r] + bv;
        if (BF16OUT)
          Outz[(row0 + rbase + r) * (long)ldo + col0 + c_] = f2bf(val);
        else if (c_ < 68)
          OutF[(row0 + rbase + r) * 68L + c_] = val;
      }
    }
  }
}

// ---------------- depthwise 3x3 + bias + fast GELU, 4 pixels/thread ----------------
// CLS: lanes 0-31 (c-branch) don't store; instead compute fc3_c dot (256ch) -> cls_logit.
template <bool CLS>
__global__ __launch_bounds__(256) void dwconv_gelu4(
    const unsigned short* __restrict__ In,
    const float* __restrict__ Wt, const float* __restrict__ Bt,
    unsigned short* __restrict__ Out,
    const unsigned short* __restrict__ Wc3, const float* __restrict__ bc3,
    float* __restrict__ cls_logit) {
  const int t = blockIdx.x * 256 + threadIdx.x;  // 32768 quads * 64 groups
  const int g = t & 63;
  const int p = t >> 6;
  const int n = p >> 10;
  const int h = (p >> 4) & 63;
  const int w0 = (p & 15) << 2;
  const int cbase = g << 3;
  f32x2 acc[4][4];
  {
    float4 b0 = *(const float4*)(Bt + cbase);
    float4 b1 = *(const float4*)(Bt + cbase + 4);
    f32x2 bb[4];
    bb[0].x = b0.x; bb[0].y = b0.y; bb[1].x = b0.z; bb[1].y = b0.w;
    bb[2].x = b1.x; bb[2].y = b1.y; bb[3].x = b1.z; bb[3].y = b1.w;
    #pragma unroll
    for (int k = 0; k < 4; k++)
      #pragma unroll
      for (int i = 0; i < 4; i++) acc[k][i] = bb[i];
  }
  #pragma unroll
  for (int dy = -1; dy <= 1; dy++) {
    const int hh = h + dy;
    if (hh < 0 || hh > 63) continue;           // wave-uniform
    const float* wbase = Wt + ((dy + 1) * 3) * 512 + cbase;
    f32x2 wt[3][4];
    #pragma unroll
    for (int j = 0; j < 3; j++) {
      float4 a0 = *(const float4*)(wbase + j * 512);
      float4 a1 = *(const float4*)(wbase + j * 512 + 4);
      wt[j][0].x = a0.x; wt[j][0].y = a0.y; wt[j][1].x = a0.z; wt[j][1].y = a0.w;
      wt[j][2].x = a1.x; wt[j][2].y = a1.y; wt[j][3].x = a1.z; wt[j][3].y = a1.w;
    }
    const long rowtok = (long)(((n << 6) + hh) << 6);
    f32x2 f[6][4];
    #pragma unroll
    for (int d = 0; d < 6; d++) {
      const int col = w0 - 1 + d;
      uint4 v = {0u, 0u, 0u, 0u};
      if (col >= 0 && col < 64)                // only d=0/d=5 can fail; wave-uniform
        v = *(const uint4*)(In + (rowtok + col) * 512 + cbase);
      f[d][0] = unpack2(v.x); f[d][1] = unpack2(v.y);
      f[d][2] = unpack2(v.z); f[d][3] = unpack2(v.w);
    }
    #pragma unroll
    for (int k = 0; k < 4; k++)
      #pragma unroll
      for (int j = 0; j < 3; j++)
        #pragma unroll
        for (int i = 0; i < 4; i++)
          acc[k][i] += f[k + j][i] * wt[j][i];
  }
  f32x2 w3[4];
  if (CLS) {
    const int cc = cbase & 255;
    uint4 wv = *(const uint4*)(Wc3 + cc);
    w3[0] = unpack2(wv.x); w3[1] = unpack2(wv.y);
    w3[2] = unpack2(wv.z); w3[3] = unpack2(wv.w);
  }
  const long mbase = ((long)((n << 6) + h) << 6) + w0;
  float s[4];
  #pragma unroll
  for (int k = 0; k < 4; k++) {
    __align__(16) unsigned int ov[4];
    f32x2 ge[4];
    #pragma unroll
    for (int i = 0; i < 4; i++) {
      ge[i] = gelu2(acc[k][i]);
      ov[i] = cvt_pk_bf16(ge[i].x, ge[i].y);
    }
    if (!CLS || cbase >= 256)
      *(uint4*)(Out + (mbase + k) * 512 + cbase) = *(uint4*)ov;
    if (CLS) {
      f32x2 sp = ge[0] * w3[0] + ge[1] * w3[1] + ge[2] * w3[2] + ge[3] * w3[3];
      s[k] = sp.x + sp.y;
    }
  }
  if (CLS) {
    #pragma unroll
    for (int k = 0; k < 4; k++) {
      #pragma unroll
      for (int m = 16; m >= 1; m >>= 1) s[k] += __shfl_xor(s[k], m);
    }
    if (g == 0) {
      float b = bc3[0];
      float4 o;
      o.x = s[0] + b; o.y = s[1] + b; o.z = s[2] + b; o.w = s[3] + b;
      *(float4*)(cls_logit + mbase) = o;
    }
  }
}

// ---------------- post: reads fp32 out_reg; softmax-17, boxes, top4, q-net, cls ---
__global__ __launch_bounds__(256) void post_kernel(
    const float* __restrict__ REG,
    const float* __restrict__ cls_logit,
    const float* __restrict__ rc1_w, const float* __restrict__ rc1_b,
    const float* __restrict__ rc2_w, const float* __restrict__ rc2_b,
    float* __restrict__ out_cls, float* __restrict__ out_boxes) {
  int m = blockIdx.x * 256 + threadIdx.x;
  const float* rp = REG + (long)m * 68;
  __align__(16) float raw[68];
  #pragma unroll
  for (int q = 0; q < 17; q++)
    *(float4*)(raw + q * 4) = *(const float4*)(rp + q * 4);
  float stat[20];
  float4 boxes;
  #pragma unroll
  for (int s = 0; s < 4; s++) {
    float v[17];
    float mx = -1e30f;
    #pragma unroll
    for (int i = 0; i < 17; i++) {
      v[i] = raw[s * 17 + i];
      mx = fmaxf(mx, v[i]);
    }
    float sum = 0.f;
    #pragma unroll
    for (int i = 0; i < 17; i++) { v[i] = __expf(v[i] - mx); sum += v[i]; }
    float inv = 1.f / sum;
    float dist = 0.f;
    #pragma unroll
    for (int i = 0; i < 17; i++) { v[i] *= inv; dist += v[i] * (float)i; }
    ((float*)&boxes)[s] = dist * 0.0625f;
    float tk[4];
    #pragma unroll
    for (int t = 0; t < 4; t++) {
      float bm = v[0]; int bi = 0;
      #pragma unroll
      for (int i = 1; i < 17; i++) {
        if (v[i] > bm) { bm = v[i]; bi = i; }
      }
      tk[t] = bm;
      #pragma unroll
      for (int i = 0; i < 17; i++)
        if (i == bi) v[i] = -1.f;
    }
    stat[s * 5 + 0] = tk[0]; stat[s * 5 + 1] = tk[1];
    stat[s * 5 + 2] = tk[2]; stat[s * 5 + 3] = tk[3];
    stat[s * 5 + 4] = 0.25f * (tk[0] + tk[1] + tk[2] + tk[3]);
  }
  *(float4*)(out_boxes + (long)m * 4) = boxes;
  float z = 0.f;
  #pragma unroll
  for (int o = 0; o < 64; o++) {
    float q = rc1_b[o];
    #pragma unroll
    for (int c = 0; c < 20; c++) q += rc1_w[o * 20 + c] * stat[c];
    q = fmaxf(q, 0.f);
    z += q * rc2_w[o];
  }
  z += rc2_b[0];
  float q2 = 1.f / (1.f + __expf(-z));
  float cl = 1.f / (1.f + __expf(-cls_logit[m]));
  out_cls[m] = cl * q2;
}

extern "C" void kernel_launch(void* const* d_in, const int* in_sizes, int n_in,
                              void* d_out, int out_size, void* d_ws, size_t ws_size,
                              hipStream_t stream) {
  const float* x       = (const float*)d_in[0];
  const float* c_fc1_w = (const float*)d_in[1];
  const float* c_fc1_b = (const float*)d_in[2];
  const float* c_dw1_w = (const float*)d_in[3];
  const float* c_dw1_b = (const float*)d_in[4];
  const float* c_fc2_w = (const float*)d_in[5];
  const float* c_fc2_b = (const float*)d_in[6];
  const float* c_dw2_w = (const float*)d_in[7];
  const float* c_dw2_b = (const float*)d_in[8];
  const float* c_fc3_w = (const float*)d_in[9];
  const float* c_fc3_b = (const float*)d_in[10];
  const float* r_fc1_w = (const float*)d_in[11];
  const float* r_fc1_b = (const float*)d_in[12];
  const float* r_dw1_w = (const float*)d_in[13];
  const float* r_dw1_b = (const float*)d_in[14];
  const float* r_fc2_w = (const float*)d_in[15];
  const float* r_fc2_b = (const float*)d_in[16];
  const float* r_dw2_w = (const float*)d_in[17];
  const float* r_dw2_b = (const float*)d_in[18];
  const float* r_fc3_w = (const float*)d_in[19];
  const float* r_fc3_b = (const float*)d_in[20];
  const float* rc1_w   = (const float*)d_in[21];
  const float* rc1_b   = (const float*)d_in[22];
  const float* rc2_w   = (const float*)d_in[23];
  const float* rc2_b   = (const float*)d_in[24];

  char* ws = (char*)d_ws;
  unsigned short* Hbuf = (unsigned short*)ws;                       // 128 MiB
  unsigned short* Gbuf = (unsigned short*)(ws + 134217728L);        // 128 MiB
  unsigned short* xb   = Gbuf;                                      // 64 MiB alias (dead after fc1)
  float* cls_logit     = (float*)(ws + 268435456L);                 // 512 KiB
  char* wb             = ws + 268959744L;
  unsigned short* w1cat  = (unsigned short*)wb;          // 131072 bf16 (c_fc1|r_fc1)
  unsigned short* w2cat  = w1cat + 131072;               // 131072 bf16 (c_fc2|r_fc2)
  unsigned short* c3wb   = w2cat + 131072;               // 256
  unsigned short* wr3pad = c3wb + 256;                   // 32768
  float* br3pad = (float*)(wr3pad + 32768);              // 128
  float* b1cat  = br3pad + 128;                          // 512
  float* b2cat  = b1cat + 512;                           // 512
  float* wd1    = b2cat + 512;                           // 4608
  float* bd1    = wd1 + 4608;                            // 512
  float* wd2    = bd1 + 512;                             // 4608
  float* bd2    = wd2 + 4608;                            // 512

  float* out_cls   = (float*)d_out;
  float* out_boxes = out_cls + 131072;
  float* out_reg   = out_boxes + 524288;

  // prep (weights) + x conversion, one dispatch
  prep_all<<<16384, 256, 0, stream>>>(
      x, xb,
      c_fc1_w, r_fc1_w, c_fc2_w, r_fc2_w, c_fc3_w, r_fc3_w, r_fc3_b,
      c_fc1_b, r_fc1_b, c_fc2_b, r_fc2_b,
      c_dw1_w, c_dw1_b, r_dw1_w, r_dw1_b,
      c_dw2_w, c_dw2_b, r_dw2_w, r_dw2_b,
      w1cat, w2cat, c3wb, wr3pad, br3pad, b1cat, b2cat,
      wd1, bd1, wd2, bd2);

  // fc1: A = xb (bf16, lda 256), N=512 (nN=4)
  gemm_glds<true><<<dim3(4096, 1, 1), 256, 0, stream>>>(
      xb, 256, 0, w1cat, 0, b1cat, 0, Hbuf, 512, 0, 2, nullptr);
  // dwconv1 + gelu (stores both halves)
  dwconv_gelu4<false><<<8192, 256, 0, stream>>>(Hbuf, wd1, bd1, Gbuf,
                                                nullptr, nullptr, nullptr);
  // fc2: branches via z (nN=2 per branch)
  gemm_glds<true><<<dim3(2048, 1, 2), 256, 0, stream>>>(
      Gbuf, 512, 256, w2cat, 65536, b2cat, 256, Hbuf, 512, 256, 1, nullptr);
  // dwconv2 + gelu + fused cls dot (stores only r-half)
  dwconv_gelu4<true><<<8192, 256, 0, stream>>>(Hbuf, wd2, bd2, Gbuf,
                                               c3wb, c_fc3_b, cls_logit);
  // fc3 (r-half): fp32 out_reg ONLY (no bf16 RP)
  gemm_glds<false><<<dim3(1024, 1, 1), 256, 0, stream>>>(
      Gbuf + 256, 512, 0, wr3pad, 0, br3pad, 0, nullptr, 128, 0, 0, out_reg);
  // post (cls + boxes from fp32 out_reg)
  post_kernel<<<512, 256, 0, stream>>>(out_reg, cls_logit, rc1_w, rc1_b, rc2_w, rc2_b,
                                       out_cls, out_boxes);
}